// Round 1
// baseline (364.908 us; speedup 1.0000x reference)
//
#include <hip/hip_runtime.h>

#define NN 20000
#define EE 640000
#define SS 256
#define DD 2000
#define PP 500
#define PHH 100

// ---------- 1. per-sample mean / inv-std (f64 accumulation) ----------
__global__ __launch_bounds__(256) void k_meanstd(
    const float* __restrict__ lnc, const float* __restrict__ mi,
    const float* __restrict__ mdat, float* __restrict__ mean,
    float* __restrict__ invstd) {
  int s = blockIdx.x, tid = threadIdx.x;
  double sum = 0.0, ssq = 0.0;
  for (int i = tid; i < 8000; i += 256) { float v = lnc[s * 8000 + i];  sum += v; ssq += (double)v * v; }
  for (int i = tid; i < 2000; i += 256) { float v = mi[s * 2000 + i];   sum += v; ssq += (double)v * v; }
  for (int i = tid; i < 10000; i += 256){ float v = mdat[s * 10000 + i]; sum += v; ssq += (double)v * v; }
  __shared__ double sm[256], sq[256];
  sm[tid] = sum; sq[tid] = ssq; __syncthreads();
  for (int o = 128; o > 0; o >>= 1) {
    if (tid < o) { sm[tid] += sm[tid + o]; sq[tid] += sq[tid + o]; }
    __syncthreads();
  }
  if (tid == 0) {
    double mu = sm[0] / 20000.0;
    double var = (sq[0] - 20000.0 * mu * mu) / 19999.0;
    mean[s] = (float)mu;
    invstd[s] = (float)(1.0 / sqrt(var));
  }
}

// ---------- 2. normalize + transpose [S,N] -> a_rna [N,S] ----------
__global__ __launch_bounds__(256) void k_transpose(
    const float* __restrict__ lnc, const float* __restrict__ mi,
    const float* __restrict__ mdat, const float* __restrict__ mean,
    const float* __restrict__ invstd, float* __restrict__ a_rna) {
  __shared__ float tile[32][33];
  int nb = blockIdx.x * 32, sb = blockIdx.y * 32;
  int tx = threadIdx.x;  // 0..31
  for (int r = threadIdx.y; r < 32; r += 8) {
    int s = sb + r, n = nb + tx;
    float v;
    if (n < 8000)       v = lnc[s * 8000 + n];
    else if (n < 10000) v = mi[s * 2000 + (n - 8000)];
    else                v = mdat[s * 10000 + (n - 10000)];
    tile[r][tx] = (v - mean[s]) * invstd[s];
  }
  __syncthreads();
  for (int r = threadIdx.y; r < 32; r += 8) {
    int n = nb + r, s = sb + tx;
    a_rna[(size_t)n * SS + s] = tile[tx][r];
  }
}

// ---------- 3. row sums -> a1, a2 ----------
__global__ __launch_bounds__(256) void k_rowsum(
    const float* __restrict__ a_rna, const float* __restrict__ attn_l,
    const float* __restrict__ attn_r, float* __restrict__ a1, float* __restrict__ a2) {
  int wave = threadIdx.x >> 6, lane = threadIdx.x & 63;
  int n = blockIdx.x * 4 + wave;
  const float4* row = (const float4*)a_rna;
  float4 v = row[(size_t)n * 64 + lane];
  float s = v.x + v.y + v.z + v.w;
  for (int o = 32; o > 0; o >>= 1) s += __shfl_down(s, o, 64);
  if (lane == 0) {
    a1[n] = attn_l[n] * s;
    a2[n] = attn_r[n] * s;
  }
}

// ---------- 4. edge gate: z-sum + degree counts ----------
__device__ __forceinline__ float hc_gate(float l) {
  float sg = 1.0f / (1.0f + __expf(-l * (1.0f / 0.66f)));
  return fminf(fmaxf(fmaf(sg, 1.2f, -0.1f), 0.0f), 1.0f);
}

__global__ __launch_bounds__(256) void k_gatecount(
    const int* __restrict__ src, const int* __restrict__ dst,
    const float* __restrict__ a1, const float* __restrict__ a2,
    const float* __restrict__ bias0, float* __restrict__ z, int* __restrict__ counts) {
  int e = blockIdx.x * 256 + threadIdx.x;
  if (e >= EE) return;
  int d = dst[e];
  float a = hc_gate(a1[src[e]] + a2[d] + bias0[0]);
  atomicAdd(&z[d], a);
  atomicAdd(&counts[d], 1);
}

// ---------- 5. exclusive scan of counts (single block) ----------
__global__ __launch_bounds__(1024) void k_scan(
    const int* __restrict__ counts, int* __restrict__ offsets, int* __restrict__ cursor) {
  __shared__ int sums[1024];
  int t = threadIdx.x;
  int base = t * 20;
  int local[20];
  int s = 0;
  for (int i = 0; i < 20; ++i) {
    int idx = base + i;
    int c = (idx < NN) ? counts[idx] : 0;
    local[i] = s; s += c;
  }
  sums[t] = s; __syncthreads();
  for (int d = 1; d < 1024; d <<= 1) {
    int v = (t >= d) ? sums[t - d] : 0;
    __syncthreads();
    sums[t] += v;
    __syncthreads();
  }
  int prefix = (t > 0) ? sums[t - 1] : 0;
  for (int i = 0; i < 20; ++i) {
    int idx = base + i;
    if (idx < NN) { int o = prefix + local[i]; offsets[idx] = o; cursor[idx] = o; }
  }
  if (t == 1023) offsets[NN] = sums[1023];
}

// ---------- 6. CSR fill with normalized gate ----------
__global__ __launch_bounds__(256) void k_fill(
    const int* __restrict__ src, const int* __restrict__ dst,
    const float* __restrict__ a1, const float* __restrict__ a2,
    const float* __restrict__ bias0, const float* __restrict__ z,
    int* __restrict__ cursor, uint2* __restrict__ csr) {
  int e = blockIdx.x * 256 + threadIdx.x;
  if (e >= EE) return;
  int d = dst[e], s = src[e];
  float a = hc_gate(a1[s] + a2[d] + bias0[0]);
  float zz = z[d];
  float g = (zz > 0.0f) ? a / zz : 0.0f;
  int slot = atomicAdd(&cursor[d], 1);
  uint2 rec; rec.x = (unsigned)s; rec.y = __float_as_uint(g);
  csr[slot] = rec;
}

// ---------- 7. pass-1 aggregation: rna1[n,:] = sum_e g * a_rna[src,:] ----------
__global__ __launch_bounds__(256) void k_agg(
    const uint2* __restrict__ csr, const int* __restrict__ offsets,
    const float* __restrict__ in_feat, float* __restrict__ out_feat) {
  int wave = threadIdx.x >> 6, lane = threadIdx.x & 63;
  int n = blockIdx.x * 4 + wave;
  const float4* in4 = (const float4*)in_feat;
  float4 acc = {0.f, 0.f, 0.f, 0.f};
  int beg = offsets[n], end = offsets[n + 1];
  for (int i = beg; i < end; ++i) {
    uint2 sg = csr[i];
    float g = __uint_as_float(sg.y);
    float4 v = in4[(size_t)sg.x * 64 + lane];
    acc.x += g * v.x; acc.y += g * v.y; acc.z += g * v.z; acc.w += g * v.w;
  }
  ((float4*)out_feat)[(size_t)n * 64 + lane] = acc;
}

// ---------- 8. fused pass-2 + x build: xt[d][s] = a_rna+rna1+rna2 at dem[d] ----------
__global__ __launch_bounds__(256) void k_pass2x(
    const int* __restrict__ dem, const int* __restrict__ offsets,
    const uint2* __restrict__ csr, const float* __restrict__ a_rna,
    const float* __restrict__ rna1, float* __restrict__ xt) {
  int wave = threadIdx.x >> 6, lane = threadIdx.x & 63;
  int d = blockIdx.x * 4 + wave;
  int nd = dem[d];
  const float4* ar = (const float4*)a_rna;
  const float4* r1 = (const float4*)rna1;
  float4 acc = ar[(size_t)nd * 64 + lane];
  float4 b = r1[(size_t)nd * 64 + lane];
  acc.x += b.x; acc.y += b.y; acc.z += b.z; acc.w += b.w;
  int beg = offsets[nd], end = offsets[nd + 1];
  for (int i = beg; i < end; ++i) {
    uint2 sg = csr[i];
    float g = __uint_as_float(sg.y);
    float4 v = r1[(size_t)sg.x * 64 + lane];
    acc.x += g * v.x; acc.y += g * v.y; acc.z += g * v.z; acc.w += g * v.w;
  }
  ((float4*)xt)[(size_t)d * 64 + lane] = acc;
}

// ---------- 9. GEMM1: h1t[p][s] += sum_d xt[d][s] * Wmp[p][d]*mask[p][d] ----------
__global__ __launch_bounds__(256) void k_gemm1(
    const float* __restrict__ xt, const float* __restrict__ Wmp,
    const float* __restrict__ pmask, float* __restrict__ h1t) {
  __shared__ float As[20][64];
  __shared__ float Ws[64][21];
  int tid = threadIdx.x;
  int s0 = blockIdx.x * 64, p0 = blockIdx.y * 64, d0 = blockIdx.z * 200;
  int ts = tid & 15, tp = tid >> 4;
  float acc[4][4];
  #pragma unroll
  for (int i = 0; i < 4; ++i)
    #pragma unroll
    for (int j = 0; j < 4; ++j) acc[i][j] = 0.f;

  for (int kt = 0; kt < 10; ++kt) {
    int dd = d0 + kt * 20;
    for (int i = tid; i < 20 * 64; i += 256) {
      int r = i >> 6, c = i & 63;
      As[r][c] = xt[(size_t)(dd + r) * SS + s0 + c];
    }
    for (int i = tid; i < 64 * 20; i += 256) {
      int r = i / 20, c = i % 20;
      int p = p0 + r;
      Ws[r][c] = (p < PP) ? Wmp[(size_t)p * DD + dd + c] * pmask[(size_t)p * DD + dd + c] : 0.f;
    }
    __syncthreads();
    #pragma unroll
    for (int kk = 0; kk < 20; ++kk) {
      float a[4], b[4];
      #pragma unroll
      for (int i = 0; i < 4; ++i) a[i] = As[kk][ts * 4 + i];
      #pragma unroll
      for (int j = 0; j < 4; ++j) b[j] = Ws[tp * 4 + j][kk];
      #pragma unroll
      for (int i = 0; i < 4; ++i)
        #pragma unroll
        for (int j = 0; j < 4; ++j) acc[i][j] += a[i] * b[j];
    }
    __syncthreads();
  }
  #pragma unroll
  for (int i = 0; i < 4; ++i) {
    int s = s0 + ts * 4 + i;
    #pragma unroll
    for (int j = 0; j < 4; ++j) {
      int p = p0 + tp * 4 + j;
      if (p < PP) atomicAdd(&h1t[(size_t)p * SS + s], acc[i][j]);
    }
  }
}

// ---------- 10. bias + relu on h1t ----------
__global__ __launch_bounds__(256) void k_biasrelu(
    float* __restrict__ h1t, const float* __restrict__ bmp) {
  int idx = blockIdx.x * 256 + threadIdx.x;
  if (idx >= PP * SS) return;
  int p = idx >> 8;
  float v = h1t[idx] + bmp[p];
  h1t[idx] = fmaxf(v, 0.0f);
}

// ---------- 11. h2t[ph][s] = relu(sum_p h1t[p][s]*Wph[ph][p] + bph[ph]) ----------
__global__ __launch_bounds__(256) void k_h2(
    const float* __restrict__ h1t, const float* __restrict__ Wph,
    const float* __restrict__ bph, float* __restrict__ h2t) {
  int ph = blockIdx.x;
  int s = threadIdx.x;
  float acc = 0.f;
  for (int p = 0; p < PP; ++p) acc += h1t[(size_t)p * SS + s] * Wph[ph * PP + p];
  h2t[(size_t)ph * SS + s] = fmaxf(acc + bph[ph], 0.0f);
}

// ---------- 12. out[s,:] = softmax(h2[s,:] @ Wpo^T + bpo) ----------
__global__ __launch_bounds__(256) void k_out(
    const float* __restrict__ h2t, const float* __restrict__ Wpo,
    const float* __restrict__ bpo, float* __restrict__ out) {
  int s = threadIdx.x;
  float o0 = bpo[0], o1 = bpo[1];
  for (int ph = 0; ph < PHH; ++ph) {
    float v = h2t[(size_t)ph * SS + s];
    o0 += v * Wpo[ph];
    o1 += v * Wpo[PHH + ph];
  }
  float mx = fmaxf(o0, o1);
  float e0 = __expf(o0 - mx), e1 = __expf(o1 - mx);
  float inv = 1.0f / (e0 + e1);
  out[2 * s] = e0 * inv;
  out[2 * s + 1] = e1 * inv;
}

extern "C" void kernel_launch(void* const* d_in, const int* in_sizes, int n_in,
                              void* d_out, int out_size, void* d_ws, size_t ws_size,
                              hipStream_t stream) {
  const float* lnc   = (const float*)d_in[0];
  const float* mi    = (const float*)d_in[1];
  const float* mdat  = (const float*)d_in[2];
  const int*   src   = (const int*)d_in[3];
  const int*   dst   = (const int*)d_in[4];
  const int*   dem   = (const int*)d_in[5];
  const float* attnl = (const float*)d_in[6];
  const float* attnr = (const float*)d_in[7];
  const float* bias0 = (const float*)d_in[8];
  const float* pmask = (const float*)d_in[9];
  const float* Wmp   = (const float*)d_in[10];
  const float* bmp   = (const float*)d_in[11];
  const float* Wph   = (const float*)d_in[12];
  const float* bph   = (const float*)d_in[13];
  const float* Wpo   = (const float*)d_in[14];
  const float* bpo   = (const float*)d_in[15];
  float* out = (float*)d_out;

  char* ws = (char*)d_ws;
  size_t off = 0;
  auto alloc = [&](size_t bytes) -> char* {
    char* p = ws + off;
    off += (bytes + 255) & ~(size_t)255;
    return p;
  };
  float* mean   = (float*)alloc(SS * 4);
  float* invstd = (float*)alloc(SS * 4);
  float* a1     = (float*)alloc(NN * 4);
  float* a2     = (float*)alloc(NN * 4);
  float* z      = (float*)alloc(NN * 4);        // zero region start
  int*   counts = (int*)alloc(NN * 4);
  int*   offs   = (int*)alloc((NN + 1) * 4);
  int*   cursor = (int*)alloc(NN * 4);
  uint2* csr    = (uint2*)alloc((size_t)EE * 8);
  float* a_rna  = (float*)alloc((size_t)NN * SS * 4);
  float* rna1   = (float*)alloc((size_t)NN * SS * 4);
  float* xt     = (float*)alloc((size_t)DD * SS * 4);
  float* h1t    = (float*)alloc((size_t)PP * SS * 4);
  float* h2t    = (float*)alloc((size_t)PHH * SS * 4);

  // zero: z, counts (contiguous-ish region), and h1t accumulator
  hipMemsetAsync(z, 0, (size_t)((char*)offs - (char*)z), stream);
  hipMemsetAsync(h1t, 0, (size_t)PP * SS * 4, stream);

  k_meanstd<<<SS, 256, 0, stream>>>(lnc, mi, mdat, mean, invstd);
  k_transpose<<<dim3(NN / 32, SS / 32), dim3(32, 8), 0, stream>>>(lnc, mi, mdat, mean, invstd, a_rna);
  k_rowsum<<<NN / 4, 256, 0, stream>>>(a_rna, attnl, attnr, a1, a2);
  k_gatecount<<<(EE + 255) / 256, 256, 0, stream>>>(src, dst, a1, a2, bias0, z, counts);
  k_scan<<<1, 1024, 0, stream>>>(counts, offs, cursor);
  k_fill<<<(EE + 255) / 256, 256, 0, stream>>>(src, dst, a1, a2, bias0, z, cursor, csr);
  k_agg<<<NN / 4, 256, 0, stream>>>(csr, offs, a_rna, rna1);
  k_pass2x<<<DD / 4, 256, 0, stream>>>(dem, offs, csr, a_rna, rna1, xt);
  k_gemm1<<<dim3(SS / 64, 8, 10), 256, 0, stream>>>(xt, Wmp, pmask, h1t);
  k_biasrelu<<<(PP * SS + 255) / 256, 256, 0, stream>>>(h1t, bmp);
  k_h2<<<PHH, SS, 0, stream>>>(h1t, Wph, bph, h2t);
  k_out<<<1, SS, 0, stream>>>(h2t, Wpo, bpo, out);
}

// Round 2
// 288.468 us; speedup vs baseline: 1.2650x; 1.2650x over previous
//
#include <hip/hip_runtime.h>

#define NN 20000
#define EE 640000
#define SS 256
#define DD 2000
#define PP 500
#define PHH 100

typedef unsigned short ushort_t;

__device__ __forceinline__ unsigned short f2bf(float f) {
  unsigned u = __float_as_uint(f);
  unsigned r = (u + 0x7FFFu + ((u >> 16) & 1u)) >> 16;  // RNE
  return (unsigned short)r;
}

// ---------- 1. per-sample mean / inv-std (f64 accumulation) ----------
__global__ __launch_bounds__(256) void k_meanstd(
    const float* __restrict__ lnc, const float* __restrict__ mi,
    const float* __restrict__ mdat, float* __restrict__ mean,
    float* __restrict__ invstd) {
  int s = blockIdx.x, tid = threadIdx.x;
  double sum = 0.0, ssq = 0.0;
  for (int i = tid; i < 8000; i += 256) { float v = lnc[s * 8000 + i];  sum += v; ssq += (double)v * v; }
  for (int i = tid; i < 2000; i += 256) { float v = mi[s * 2000 + i];   sum += v; ssq += (double)v * v; }
  for (int i = tid; i < 10000; i += 256){ float v = mdat[s * 10000 + i]; sum += v; ssq += (double)v * v; }
  __shared__ double sm[256], sq[256];
  sm[tid] = sum; sq[tid] = ssq; __syncthreads();
  for (int o = 128; o > 0; o >>= 1) {
    if (tid < o) { sm[tid] += sm[tid + o]; sq[tid] += sq[tid + o]; }
    __syncthreads();
  }
  if (tid == 0) {
    double mu = sm[0] / 20000.0;
    double var = (sq[0] - 20000.0 * mu * mu) / 19999.0;
    mean[s] = (float)mu;
    invstd[s] = (float)(1.0 / sqrt(var));
  }
}

// ---------- 2. a1/a2 directly from [S,N] layout (no transpose needed) ----------
// a1[n] = attn_l[n] * (sum_s invstd[s]*raw[s][n] - sum_s invstd[s]*mean[s])
__global__ __launch_bounds__(256) void k_a1a2(
    const float* __restrict__ lnc, const float* __restrict__ mi,
    const float* __restrict__ mdat, const float* __restrict__ mean,
    const float* __restrict__ invstd, const float* __restrict__ attnl,
    const float* __restrict__ attnr, float* __restrict__ a1, float* __restrict__ a2) {
  __shared__ float sinv[256];
  __shared__ float red[256];
  int tid = threadIdx.x;
  float iv = invstd[tid];
  sinv[tid] = iv;
  red[tid] = iv * mean[tid];
  __syncthreads();
  for (int o = 128; o > 0; o >>= 1) {
    if (tid < o) red[tid] += red[tid + o];
    __syncthreads();
  }
  float C = red[0];
  int n = blockIdx.x * 256 + tid;
  if (n >= NN) return;
  const float* base; int w, c;
  if (n < 8000)       { base = lnc;  w = 8000;  c = n; }
  else if (n < 10000) { base = mi;   w = 2000;  c = n - 8000; }
  else                { base = mdat; w = 10000; c = n - 10000; }
  float acc = 0.f;
  #pragma unroll 4
  for (int s = 0; s < 256; ++s) acc = fmaf(base[(size_t)s * w + c], sinv[s], acc);
  float t = acc - C;
  a1[n] = attnl[n] * t;
  a2[n] = attnr[n] * t;
}

// ---------- 3. normalize + transpose -> a_rna bf16 [N, S] ----------
__global__ __launch_bounds__(256) void k_transpose(
    const float* __restrict__ lnc, const float* __restrict__ mi,
    const float* __restrict__ mdat, const float* __restrict__ mean,
    const float* __restrict__ invstd, ushort_t* __restrict__ a_rna) {
  __shared__ float tile[64][33];  // [s][n]
  int nb = blockIdx.x * 32, sb = blockIdx.y * 64;
  int tx = threadIdx.x;  // 0..31 (n within tile)
  // block's 32-col range never straddles matrix boundary (8000, 10000 are /32)
  int n = nb + tx;
  const float* base; int w, c;
  if (n < 8000)       { base = lnc;  w = 8000;  c = n; }
  else if (n < 10000) { base = mi;   w = 2000;  c = n - 8000; }
  else                { base = mdat; w = 10000; c = n - 10000; }
  for (int r = threadIdx.y; r < 64; r += 8) {
    int s = sb + r;
    tile[r][tx] = (base[(size_t)s * w + c] - mean[s]) * invstd[s];
  }
  __syncthreads();
  // write: row n gets 64 s-values = 32 threads x ushort2
  ushort2* out2 = (ushort2*)a_rna;
  for (int r2 = threadIdx.y; r2 < 32; r2 += 8) {
    int nn = nb + r2;
    ushort2 v;
    v.x = f2bf(tile[2 * tx][r2]);
    v.y = f2bf(tile[2 * tx + 1][r2]);
    out2[(size_t)nn * 128 + (sb >> 1) + tx] = v;
  }
}

// ---------- 4. degree counts ----------
__global__ __launch_bounds__(256) void k_count(
    const int* __restrict__ dst, int* __restrict__ counts) {
  int e = blockIdx.x * 256 + threadIdx.x;
  if (e >= EE) return;
  atomicAdd(&counts[dst[e]], 1);
}

// ---------- 5. exclusive scan of counts (single block) ----------
__global__ __launch_bounds__(1024) void k_scan(
    const int* __restrict__ counts, int* __restrict__ offsets, int* __restrict__ cursor) {
  __shared__ int sums[1024];
  int t = threadIdx.x;
  int base = t * 20;
  int local[20];
  int s = 0;
  for (int i = 0; i < 20; ++i) {
    int idx = base + i;
    int c = (idx < NN) ? counts[idx] : 0;
    local[i] = s; s += c;
  }
  sums[t] = s; __syncthreads();
  for (int d = 1; d < 1024; d <<= 1) {
    int v = (t >= d) ? sums[t - d] : 0;
    __syncthreads();
    sums[t] += v;
    __syncthreads();
  }
  int prefix = (t > 0) ? sums[t - 1] : 0;
  for (int i = 0; i < 20; ++i) {
    int idx = base + i;
    if (idx < NN) { int o = prefix + local[i]; offsets[idx] = o; cursor[idx] = o; }
  }
  if (t == 1023) offsets[NN] = sums[1023];
}

// ---------- 6. CSR fill with raw (unnormalized) gate ----------
__device__ __forceinline__ float hc_gate(float l) {
  float sg = 1.0f / (1.0f + __expf(-l * 1.5151515151f));
  return fminf(fmaxf(fmaf(sg, 1.2f, -0.1f), 0.0f), 1.0f);
}

__global__ __launch_bounds__(256) void k_fill(
    const int* __restrict__ src, const int* __restrict__ dst,
    const float* __restrict__ a1, const float* __restrict__ a2,
    const float* __restrict__ bias0, int* __restrict__ cursor,
    uint2* __restrict__ csr) {
  int e = blockIdx.x * 256 + threadIdx.x;
  if (e >= EE) return;
  int d = dst[e], s = src[e];
  float a = hc_gate(a1[s] + a2[d] + bias0[0]);
  int slot = atomicAdd(&cursor[d], 1);
  uint2 rec; rec.x = (unsigned)s; rec.y = __float_as_uint(a);
  csr[slot] = rec;
}

// ---------- 7. per-dst normalize gates in place ----------
__global__ __launch_bounds__(256) void k_znorm(
    const int* __restrict__ offs, uint2* __restrict__ csr) {
  int wave = threadIdx.x >> 6, lane = threadIdx.x & 63;
  int n = blockIdx.x * 4 + wave;
  int beg = offs[n], end = offs[n + 1];
  float z = 0.f;
  for (int i = beg + lane; i < end; i += 64) z += __uint_as_float(csr[i].y);
  for (int o = 1; o < 64; o <<= 1) z += __shfl_xor(z, o, 64);
  float inv = (z > 0.f) ? 1.0f / z : 0.0f;
  for (int i = beg + lane; i < end; i += 64) {
    uint2 rec = csr[i];
    rec.y = __float_as_uint(__uint_as_float(rec.y) * inv);
    csr[i] = rec;
  }
}

// ---------- 8. pass-1 aggregation (bf16 gather): rna1 = sum g * a_rna[src] ----------
__global__ __launch_bounds__(256) void k_agg(
    const uint2* __restrict__ csr, const int* __restrict__ offs,
    const ushort_t* __restrict__ in_bf, ushort_t* __restrict__ out_bf) {
  int wave = threadIdx.x >> 6, lane = threadIdx.x & 63;
  int n = blockIdx.x * 4 + wave;
  int beg = __builtin_amdgcn_readfirstlane(offs[n]);
  int end = __builtin_amdgcn_readfirstlane(offs[n + 1]);
  const uint2* in2 = (const uint2*)in_bf;  // 4 bf16 per uint2, row = 64 uint2
  float a0 = 0.f, a1 = 0.f, a2 = 0.f, a3 = 0.f;
  int i = beg;
  for (; i + 1 < end; i += 2) {
    uint2 r0 = csr[i], r1 = csr[i + 1];
    uint2 v0 = in2[(size_t)r0.x * 64 + lane];
    uint2 v1 = in2[(size_t)r1.x * 64 + lane];
    float g0 = __uint_as_float(r0.y), g1 = __uint_as_float(r1.y);
    a0 += g0 * __uint_as_float(v0.x << 16) + g1 * __uint_as_float(v1.x << 16);
    a1 += g0 * __uint_as_float(v0.x & 0xFFFF0000u) + g1 * __uint_as_float(v1.x & 0xFFFF0000u);
    a2 += g0 * __uint_as_float(v0.y << 16) + g1 * __uint_as_float(v1.y << 16);
    a3 += g0 * __uint_as_float(v0.y & 0xFFFF0000u) + g1 * __uint_as_float(v1.y & 0xFFFF0000u);
  }
  if (i < end) {
    uint2 r0 = csr[i];
    uint2 v0 = in2[(size_t)r0.x * 64 + lane];
    float g0 = __uint_as_float(r0.y);
    a0 += g0 * __uint_as_float(v0.x << 16);
    a1 += g0 * __uint_as_float(v0.x & 0xFFFF0000u);
    a2 += g0 * __uint_as_float(v0.y << 16);
    a3 += g0 * __uint_as_float(v0.y & 0xFFFF0000u);
  }
  uint2 w;
  w.x = (unsigned)f2bf(a0) | ((unsigned)f2bf(a1) << 16);
  w.y = (unsigned)f2bf(a2) | ((unsigned)f2bf(a3) << 16);
  ((uint2*)out_bf)[(size_t)n * 64 + lane] = w;
}

// ---------- 9. fused pass-2 + x build: xt[d][s] f32 ----------
__global__ __launch_bounds__(256) void k_pass2x(
    const int* __restrict__ dem, const int* __restrict__ offs,
    const uint2* __restrict__ csr, const ushort_t* __restrict__ a_rna,
    const ushort_t* __restrict__ rna1, float* __restrict__ xt) {
  int wave = threadIdx.x >> 6, lane = threadIdx.x & 63;
  int d = blockIdx.x * 4 + wave;
  int nd = dem[d];
  const uint2* ar = (const uint2*)a_rna;
  const uint2* r1 = (const uint2*)rna1;
  uint2 va = ar[(size_t)nd * 64 + lane];
  uint2 vb = r1[(size_t)nd * 64 + lane];
  float a0 = __uint_as_float(va.x << 16) + __uint_as_float(vb.x << 16);
  float a1 = __uint_as_float(va.x & 0xFFFF0000u) + __uint_as_float(vb.x & 0xFFFF0000u);
  float a2 = __uint_as_float(va.y << 16) + __uint_as_float(vb.y << 16);
  float a3 = __uint_as_float(va.y & 0xFFFF0000u) + __uint_as_float(vb.y & 0xFFFF0000u);
  int beg = __builtin_amdgcn_readfirstlane(offs[nd]);
  int end = __builtin_amdgcn_readfirstlane(offs[nd + 1]);
  for (int i = beg; i < end; ++i) {
    uint2 rec = csr[i];
    float g = __uint_as_float(rec.y);
    uint2 v = r1[(size_t)rec.x * 64 + lane];
    a0 += g * __uint_as_float(v.x << 16);
    a1 += g * __uint_as_float(v.x & 0xFFFF0000u);
    a2 += g * __uint_as_float(v.y << 16);
    a3 += g * __uint_as_float(v.y & 0xFFFF0000u);
  }
  float4 o; o.x = a0; o.y = a1; o.z = a2; o.w = a3;
  ((float4*)xt)[(size_t)d * 64 + lane] = o;
}

// ---------- 10. GEMM1 partials: partial[z][p][s] (no atomics) ----------
__global__ __launch_bounds__(256) void k_gemm1(
    const float* __restrict__ xt, const float* __restrict__ Wmp,
    const float* __restrict__ pmask, float* __restrict__ partial) {
  __shared__ float As[20][64];
  __shared__ float Ws[64][21];
  int tid = threadIdx.x;
  int s0 = blockIdx.x * 64, p0 = blockIdx.y * 64, d0 = blockIdx.z * 200;
  int ts = tid & 15, tp = tid >> 4;
  float acc[4][4];
  #pragma unroll
  for (int i = 0; i < 4; ++i)
    #pragma unroll
    for (int j = 0; j < 4; ++j) acc[i][j] = 0.f;

  for (int kt = 0; kt < 10; ++kt) {
    int dd = d0 + kt * 20;
    for (int i = tid; i < 20 * 64; i += 256) {
      int r = i >> 6, c = i & 63;
      As[r][c] = xt[(size_t)(dd + r) * SS + s0 + c];
    }
    for (int i = tid; i < 64 * 20; i += 256) {
      int r = i / 20, c = i % 20;
      int p = p0 + r;
      Ws[r][c] = (p < PP) ? Wmp[(size_t)p * DD + dd + c] * pmask[(size_t)p * DD + dd + c] : 0.f;
    }
    __syncthreads();
    #pragma unroll
    for (int kk = 0; kk < 20; ++kk) {
      float a[4], b[4];
      #pragma unroll
      for (int i = 0; i < 4; ++i) a[i] = As[kk][ts * 4 + i];
      #pragma unroll
      for (int j = 0; j < 4; ++j) b[j] = Ws[tp * 4 + j][kk];
      #pragma unroll
      for (int i = 0; i < 4; ++i)
        #pragma unroll
        for (int j = 0; j < 4; ++j) acc[i][j] += a[i] * b[j];
    }
    __syncthreads();
  }
  float* dstp = partial + (size_t)blockIdx.z * 512 * 256;
  #pragma unroll
  for (int i = 0; i < 4; ++i) {
    int s = s0 + ts * 4 + i;
    #pragma unroll
    for (int j = 0; j < 4; ++j) {
      int p = p0 + tp * 4 + j;
      dstp[(size_t)p * 256 + s] = acc[i][j];
    }
  }
}

// ---------- 11. reduce partials + bias + relu ----------
__global__ __launch_bounds__(256) void k_reduce(
    const float* __restrict__ partial, const float* __restrict__ bmp,
    float* __restrict__ h1t) {
  int idx = blockIdx.x * 256 + threadIdx.x;
  if (idx >= PP * SS) return;
  float acc = bmp[idx >> 8];
  #pragma unroll
  for (int z = 0; z < 10; ++z) acc += partial[(size_t)z * 512 * 256 + idx];
  h1t[idx] = fmaxf(acc, 0.0f);
}

// ---------- 12. h2t[ph][s] = relu(sum_p h1t[p][s]*Wph[ph][p] + bph[ph]) ----------
__global__ __launch_bounds__(256) void k_h2(
    const float* __restrict__ h1t, const float* __restrict__ Wph,
    const float* __restrict__ bph, float* __restrict__ h2t) {
  int ph = blockIdx.x;
  int s = threadIdx.x;
  float acc = 0.f;
  for (int p = 0; p < PP; ++p) acc += h1t[(size_t)p * SS + s] * Wph[ph * PP + p];
  h2t[(size_t)ph * SS + s] = fmaxf(acc + bph[ph], 0.0f);
}

// ---------- 13. out[s,:] = softmax ----------
__global__ __launch_bounds__(256) void k_out(
    const float* __restrict__ h2t, const float* __restrict__ Wpo,
    const float* __restrict__ bpo, float* __restrict__ out) {
  int s = threadIdx.x;
  float o0 = bpo[0], o1 = bpo[1];
  for (int ph = 0; ph < PHH; ++ph) {
    float v = h2t[(size_t)ph * SS + s];
    o0 += v * Wpo[ph];
    o1 += v * Wpo[PHH + ph];
  }
  float mx = fmaxf(o0, o1);
  float e0 = __expf(o0 - mx), e1 = __expf(o1 - mx);
  float inv = 1.0f / (e0 + e1);
  out[2 * s] = e0 * inv;
  out[2 * s + 1] = e1 * inv;
}

extern "C" void kernel_launch(void* const* d_in, const int* in_sizes, int n_in,
                              void* d_out, int out_size, void* d_ws, size_t ws_size,
                              hipStream_t stream) {
  const float* lnc   = (const float*)d_in[0];
  const float* mi    = (const float*)d_in[1];
  const float* mdat  = (const float*)d_in[2];
  const int*   src   = (const int*)d_in[3];
  const int*   dst   = (const int*)d_in[4];
  const int*   dem   = (const int*)d_in[5];
  const float* attnl = (const float*)d_in[6];
  const float* attnr = (const float*)d_in[7];
  const float* bias0 = (const float*)d_in[8];
  const float* pmask = (const float*)d_in[9];
  const float* Wmp   = (const float*)d_in[10];
  const float* bmp   = (const float*)d_in[11];
  const float* Wph   = (const float*)d_in[12];
  const float* bph   = (const float*)d_in[13];
  const float* Wpo   = (const float*)d_in[14];
  const float* bpo   = (const float*)d_in[15];
  float* out = (float*)d_out;

  char* ws = (char*)d_ws;
  size_t off = 0;
  auto alloc = [&](size_t bytes) -> char* {
    char* p = ws + off;
    off += (bytes + 255) & ~(size_t)255;
    return p;
  };
  float*    mean    = (float*)alloc(SS * 4);
  float*    invstd  = (float*)alloc(SS * 4);
  float*    a1      = (float*)alloc(NN * 4);
  float*    a2      = (float*)alloc(NN * 4);
  int*      counts  = (int*)alloc(NN * 4);
  int*      offs    = (int*)alloc((NN + 1) * 4);
  int*      cursor  = (int*)alloc(NN * 4);
  uint2*    csr     = (uint2*)alloc((size_t)EE * 8);
  ushort_t* a_rna   = (ushort_t*)alloc((size_t)NN * SS * 2);
  ushort_t* rna1    = (ushort_t*)alloc((size_t)NN * SS * 2);
  float*    xt      = (float*)alloc((size_t)DD * SS * 4);
  float*    partial = (float*)alloc((size_t)10 * 512 * 256 * 4);
  float*    h1t     = (float*)alloc((size_t)PP * SS * 4);
  float*    h2t     = (float*)alloc((size_t)PHH * SS * 4);

  hipMemsetAsync(counts, 0, NN * 4, stream);

  k_meanstd<<<SS, 256, 0, stream>>>(lnc, mi, mdat, mean, invstd);
  k_a1a2<<<(NN + 255) / 256, 256, 0, stream>>>(lnc, mi, mdat, mean, invstd, attnl, attnr, a1, a2);
  k_transpose<<<dim3(NN / 32, SS / 64), dim3(32, 8), 0, stream>>>(lnc, mi, mdat, mean, invstd, a_rna);
  k_count<<<(EE + 255) / 256, 256, 0, stream>>>(dst, counts);
  k_scan<<<1, 1024, 0, stream>>>(counts, offs, cursor);
  k_fill<<<(EE + 255) / 256, 256, 0, stream>>>(src, dst, a1, a2, bias0, cursor, csr);
  k_znorm<<<NN / 4, 256, 0, stream>>>(offs, csr);
  k_agg<<<NN / 4, 256, 0, stream>>>(csr, offs, a_rna, rna1);
  k_pass2x<<<DD / 4, 256, 0, stream>>>(dem, offs, csr, a_rna, rna1, xt);
  k_gemm1<<<dim3(SS / 64, 8, 10), 256, 0, stream>>>(xt, Wmp, pmask, partial);
  k_reduce<<<(PP * SS + 255) / 256, 256, 0, stream>>>(partial, bmp, h1t);
  k_h2<<<PHH, SS, 0, stream>>>(h1t, Wph, bph, h2t);
  k_out<<<1, SS, 0, stream>>>(h2t, Wpo, bpo, out);
}

// Round 3
// 235.388 us; speedup vs baseline: 1.5502x; 1.2255x over previous
//
#include <hip/hip_runtime.h>

#define NN 20000
#define EE 640000
#define SS 256
#define DD 2000
#define PP 500
#define PHH 100
#define ZSPLIT 25
#define KCH 80
#define SUB 10

typedef unsigned short ushort_t;

__device__ __forceinline__ unsigned short f2bf(float f) {
  unsigned u = __float_as_uint(f);
  unsigned r = (u + 0x7FFFu + ((u >> 16) & 1u)) >> 16;  // RNE
  return (unsigned short)r;
}
__device__ __forceinline__ float lo16(unsigned u) { return __uint_as_float(u << 16); }
__device__ __forceinline__ float hi16(unsigned u) { return __uint_as_float(u & 0xFFFF0000u); }

// ---------- 1. per-sample mean / inv-std (f64 accumulation) ----------
__global__ __launch_bounds__(256) void k_meanstd(
    const float* __restrict__ lnc, const float* __restrict__ mi,
    const float* __restrict__ mdat, float* __restrict__ mean,
    float* __restrict__ invstd) {
  int s = blockIdx.x, tid = threadIdx.x;
  double sum = 0.0, ssq = 0.0;
  for (int i = tid; i < 8000; i += 256) { float v = lnc[s * 8000 + i];  sum += v; ssq += (double)v * v; }
  for (int i = tid; i < 2000; i += 256) { float v = mi[s * 2000 + i];   sum += v; ssq += (double)v * v; }
  for (int i = tid; i < 10000; i += 256){ float v = mdat[s * 10000 + i]; sum += v; ssq += (double)v * v; }
  __shared__ double sm[256], sq[256];
  sm[tid] = sum; sq[tid] = ssq; __syncthreads();
  for (int o = 128; o > 0; o >>= 1) {
    if (tid < o) { sm[tid] += sm[tid + o]; sq[tid] += sq[tid + o]; }
    __syncthreads();
  }
  if (tid == 0) {
    double mu = sm[0] / 20000.0;
    double var = (sq[0] - 20000.0 * mu * mu) / 19999.0;
    mean[s] = (float)mu;
    invstd[s] = (float)(1.0 / sqrt(var));
  }
}

// ---------- 2. normalize + transpose -> a_rna bf16 [N,S], fused row-sum ----------
__global__ __launch_bounds__(256) void k_transpose(
    const float* __restrict__ lnc, const float* __restrict__ mi,
    const float* __restrict__ mdat, const float* __restrict__ mean,
    const float* __restrict__ invstd, ushort_t* __restrict__ a_rna,
    float* __restrict__ rowsum) {
  __shared__ float tile[64][33];  // [s][n]
  __shared__ float red[8][33];
  int nb = blockIdx.x * 32, sb = blockIdx.y * 64;
  int tx = threadIdx.x, ty = threadIdx.y;
  int n = nb + tx;
  const float* base; int w, c;
  if (n < 8000)       { base = lnc;  w = 8000;  c = n; }
  else if (n < 10000) { base = mi;   w = 2000;  c = n - 8000; }
  else                { base = mdat; w = 10000; c = n - 10000; }
  for (int r = ty; r < 64; r += 8) {
    int s = sb + r;
    tile[r][tx] = (base[(size_t)s * w + c] - mean[s]) * invstd[s];
  }
  __syncthreads();
  // partial row sums (over this 64-s slab) for each of the 32 n's
  float ps = 0.f;
  for (int r = ty; r < 64; r += 8) ps += tile[r][tx];
  red[ty][tx] = ps;
  __syncthreads();
  if (ty == 0) {
    float t = 0.f;
    #pragma unroll
    for (int j = 0; j < 8; ++j) t += red[j][tx];
    atomicAdd(&rowsum[nb + tx], t);
  }
  // bf16 transpose write
  ushort2* out2 = (ushort2*)a_rna;
  for (int r2 = ty; r2 < 32; r2 += 8) {
    int nn = nb + r2;
    ushort2 v;
    v.x = f2bf(tile[2 * tx][r2]);
    v.y = f2bf(tile[2 * tx + 1][r2]);
    out2[(size_t)nn * 128 + (sb >> 1) + tx] = v;
  }
}

// ---------- 3. a1/a2 from rowsum ----------
__global__ __launch_bounds__(256) void k_a1a2f(
    const float* __restrict__ rowsum, const float* __restrict__ attnl,
    const float* __restrict__ attnr, float* __restrict__ a1, float* __restrict__ a2) {
  int n = blockIdx.x * 256 + threadIdx.x;
  if (n >= NN) return;
  float t = rowsum[n];
  a1[n] = attnl[n] * t;
  a2[n] = attnr[n] * t;
}

// ---------- 4. degree counts ----------
__global__ __launch_bounds__(256) void k_count(
    const int* __restrict__ dst, int* __restrict__ counts) {
  int e = blockIdx.x * 256 + threadIdx.x;
  if (e >= EE) return;
  atomicAdd(&counts[dst[e]], 1);
}

// ---------- 5. exclusive scan of counts (single block) ----------
__global__ __launch_bounds__(1024) void k_scan(
    const int* __restrict__ counts, int* __restrict__ offsets, int* __restrict__ cursor) {
  __shared__ int sums[1024];
  int t = threadIdx.x;
  int base = t * 20;
  int local[20];
  int s = 0;
  for (int i = 0; i < 20; ++i) {
    int idx = base + i;
    int c = (idx < NN) ? counts[idx] : 0;
    local[i] = s; s += c;
  }
  sums[t] = s; __syncthreads();
  for (int d = 1; d < 1024; d <<= 1) {
    int v = (t >= d) ? sums[t - d] : 0;
    __syncthreads();
    sums[t] += v;
    __syncthreads();
  }
  int prefix = (t > 0) ? sums[t - 1] : 0;
  for (int i = 0; i < 20; ++i) {
    int idx = base + i;
    if (idx < NN) { int o = prefix + local[i]; offsets[idx] = o; cursor[idx] = o; }
  }
  if (t == 1023) offsets[NN] = sums[1023];
}

// ---------- 6. CSR fill with raw (unnormalized) gate ----------
__device__ __forceinline__ float hc_gate(float l) {
  float sg = 1.0f / (1.0f + __expf(-l * 1.5151515151f));
  return fminf(fmaxf(fmaf(sg, 1.2f, -0.1f), 0.0f), 1.0f);
}

__global__ __launch_bounds__(256) void k_fill(
    const int* __restrict__ src, const int* __restrict__ dst,
    const float* __restrict__ a1, const float* __restrict__ a2,
    const float* __restrict__ bias0, int* __restrict__ cursor,
    uint2* __restrict__ csr) {
  int e = blockIdx.x * 256 + threadIdx.x;
  if (e >= EE) return;
  int d = dst[e], s = src[e];
  float a = hc_gate(a1[s] + a2[d] + bias0[0]);
  int slot = atomicAdd(&cursor[d], 1);
  uint2 rec; rec.x = (unsigned)s; rec.y = __float_as_uint(a);
  csr[slot] = rec;
}

// ---------- 7. per-dst normalize gates in place ----------
__global__ __launch_bounds__(256) void k_znorm(
    const int* __restrict__ offs, uint2* __restrict__ csr) {
  int wave = threadIdx.x >> 6, lane = threadIdx.x & 63;
  int n = blockIdx.x * 4 + wave;
  int beg = offs[n], end = offs[n + 1];
  float z = 0.f;
  for (int i = beg + lane; i < end; i += 64) z += __uint_as_float(csr[i].y);
  for (int o = 1; o < 64; o <<= 1) z += __shfl_xor(z, o, 64);
  float inv = (z > 0.f) ? 1.0f / z : 0.0f;
  for (int i = beg + lane; i < end; i += 64) {
    uint2 rec = csr[i];
    rec.y = __float_as_uint(__uint_as_float(rec.y) * inv);
    csr[i] = rec;
  }
}

// ---------- 8. pass-1 aggregation: paired b128 gather ----------
__global__ __launch_bounds__(256) void k_agg(
    const uint2* __restrict__ csr, const int* __restrict__ offs,
    const ushort_t* __restrict__ in_bf, ushort_t* __restrict__ out_bf) {
  int wave = threadIdx.x >> 6, lane = threadIdx.x & 63;
  int half = lane >> 5, sl = lane & 31;
  int n = blockIdx.x * 4 + wave;
  int beg = __builtin_amdgcn_readfirstlane(offs[n]);
  int end = __builtin_amdgcn_readfirstlane(offs[n + 1]);
  const uint4* in4 = (const uint4*)in_bf;  // 8 bf16 per uint4, row = 32 uint4
  float acc[8] = {0.f, 0.f, 0.f, 0.f, 0.f, 0.f, 0.f, 0.f};
  int i = beg;
  for (; i + 3 < end; i += 4) {
    uint2 rA = csr[i + half];
    uint2 rB = csr[i + 2 + half];
    uint4 vA = in4[(size_t)rA.x * 32 + sl];
    uint4 vB = in4[(size_t)rB.x * 32 + sl];
    float gA = __uint_as_float(rA.y), gB = __uint_as_float(rB.y);
    acc[0] += gA * lo16(vA.x) + gB * lo16(vB.x);
    acc[1] += gA * hi16(vA.x) + gB * hi16(vB.x);
    acc[2] += gA * lo16(vA.y) + gB * lo16(vB.y);
    acc[3] += gA * hi16(vA.y) + gB * hi16(vB.y);
    acc[4] += gA * lo16(vA.z) + gB * lo16(vB.z);
    acc[5] += gA * hi16(vA.z) + gB * hi16(vB.z);
    acc[6] += gA * lo16(vA.w) + gB * lo16(vB.w);
    acc[7] += gA * hi16(vA.w) + gB * hi16(vB.w);
  }
  for (; i + 1 < end; i += 2) {
    uint2 rA = csr[i + half];
    uint4 vA = in4[(size_t)rA.x * 32 + sl];
    float gA = __uint_as_float(rA.y);
    acc[0] += gA * lo16(vA.x); acc[1] += gA * hi16(vA.x);
    acc[2] += gA * lo16(vA.y); acc[3] += gA * hi16(vA.y);
    acc[4] += gA * lo16(vA.z); acc[5] += gA * hi16(vA.z);
    acc[6] += gA * lo16(vA.w); acc[7] += gA * hi16(vA.w);
  }
  if (i < end && half == 0) {
    uint2 rA = csr[i];
    uint4 vA = in4[(size_t)rA.x * 32 + sl];
    float gA = __uint_as_float(rA.y);
    acc[0] += gA * lo16(vA.x); acc[1] += gA * hi16(vA.x);
    acc[2] += gA * lo16(vA.y); acc[3] += gA * hi16(vA.y);
    acc[4] += gA * lo16(vA.z); acc[5] += gA * hi16(vA.z);
    acc[6] += gA * lo16(vA.w); acc[7] += gA * hi16(vA.w);
  }
  #pragma unroll
  for (int j = 0; j < 8; ++j) acc[j] += __shfl_xor(acc[j], 32, 64);
  if (half == 0) {
    uint4 w;
    w.x = (unsigned)f2bf(acc[0]) | ((unsigned)f2bf(acc[1]) << 16);
    w.y = (unsigned)f2bf(acc[2]) | ((unsigned)f2bf(acc[3]) << 16);
    w.z = (unsigned)f2bf(acc[4]) | ((unsigned)f2bf(acc[5]) << 16);
    w.w = (unsigned)f2bf(acc[6]) | ((unsigned)f2bf(acc[7]) << 16);
    ((uint4*)out_bf)[(size_t)n * 32 + sl] = w;
  }
}

// ---------- 9. fused pass-2 + x build: xt[d][s] f32 ----------
__global__ __launch_bounds__(256) void k_pass2x(
    const int* __restrict__ dem, const int* __restrict__ offs,
    const uint2* __restrict__ csr, const ushort_t* __restrict__ a_rna,
    const ushort_t* __restrict__ rna1, float* __restrict__ xt) {
  int wave = threadIdx.x >> 6, lane = threadIdx.x & 63;
  int half = lane >> 5, sl = lane & 31;
  int d = blockIdx.x * 4 + wave;
  int nd = dem[d];
  const uint4* ar = (const uint4*)a_rna;
  const uint4* r1 = (const uint4*)rna1;
  int beg = __builtin_amdgcn_readfirstlane(offs[nd]);
  int end = __builtin_amdgcn_readfirstlane(offs[nd + 1]);
  float acc[8] = {0.f, 0.f, 0.f, 0.f, 0.f, 0.f, 0.f, 0.f};
  int i = beg;
  for (; i + 3 < end; i += 4) {
    uint2 rA = csr[i + half];
    uint2 rB = csr[i + 2 + half];
    uint4 vA = r1[(size_t)rA.x * 32 + sl];
    uint4 vB = r1[(size_t)rB.x * 32 + sl];
    float gA = __uint_as_float(rA.y), gB = __uint_as_float(rB.y);
    acc[0] += gA * lo16(vA.x) + gB * lo16(vB.x);
    acc[1] += gA * hi16(vA.x) + gB * hi16(vB.x);
    acc[2] += gA * lo16(vA.y) + gB * lo16(vB.y);
    acc[3] += gA * hi16(vA.y) + gB * hi16(vB.y);
    acc[4] += gA * lo16(vA.z) + gB * lo16(vB.z);
    acc[5] += gA * hi16(vA.z) + gB * hi16(vB.z);
    acc[6] += gA * lo16(vA.w) + gB * lo16(vB.w);
    acc[7] += gA * hi16(vA.w) + gB * hi16(vB.w);
  }
  for (; i + 1 < end; i += 2) {
    uint2 rA = csr[i + half];
    uint4 vA = r1[(size_t)rA.x * 32 + sl];
    float gA = __uint_as_float(rA.y);
    acc[0] += gA * lo16(vA.x); acc[1] += gA * hi16(vA.x);
    acc[2] += gA * lo16(vA.y); acc[3] += gA * hi16(vA.y);
    acc[4] += gA * lo16(vA.z); acc[5] += gA * hi16(vA.z);
    acc[6] += gA * lo16(vA.w); acc[7] += gA * hi16(vA.w);
  }
  if (i < end && half == 0) {
    uint2 rA = csr[i];
    uint4 vA = r1[(size_t)rA.x * 32 + sl];
    float gA = __uint_as_float(rA.y);
    acc[0] += gA * lo16(vA.x); acc[1] += gA * hi16(vA.x);
    acc[2] += gA * lo16(vA.y); acc[3] += gA * hi16(vA.y);
    acc[4] += gA * lo16(vA.z); acc[5] += gA * hi16(vA.z);
    acc[6] += gA * lo16(vA.w); acc[7] += gA * hi16(vA.w);
  }
  #pragma unroll
  for (int j = 0; j < 8; ++j) acc[j] += __shfl_xor(acc[j], 32, 64);
  if (half == 0) {
    uint4 va = ar[(size_t)nd * 32 + sl];
    uint4 vb = r1[(size_t)nd * 32 + sl];
    acc[0] += lo16(va.x) + lo16(vb.x); acc[1] += hi16(va.x) + hi16(vb.x);
    acc[2] += lo16(va.y) + lo16(vb.y); acc[3] += hi16(va.y) + hi16(vb.y);
    acc[4] += lo16(va.z) + lo16(vb.z); acc[5] += hi16(va.z) + hi16(vb.z);
    acc[6] += lo16(va.w) + lo16(vb.w); acc[7] += hi16(va.w) + hi16(vb.w);
    float4* xo = (float4*)&xt[(size_t)d * SS + sl * 8];
    float4 w0; w0.x = acc[0]; w0.y = acc[1]; w0.z = acc[2]; w0.w = acc[3];
    float4 w1; w1.x = acc[4]; w1.y = acc[5]; w1.z = acc[6]; w1.w = acc[7];
    xo[0] = w0; xo[1] = w1;
  }
}

// ---------- 10. masked weight transpose: Wt[d][p] (p zero-padded to 512) ----------
__global__ __launch_bounds__(256) void k_maskw(
    const float* __restrict__ Wmp, const float* __restrict__ pmask,
    float* __restrict__ Wt) {
  __shared__ float tile[32][33];
  int p0 = blockIdx.x * 32, d0 = blockIdx.y * 32;
  int tx = threadIdx.x, ty = threadIdx.y;
  for (int r = ty; r < 32; r += 8) {
    int p = p0 + r, d = d0 + tx;
    float v = 0.f;
    if (p < PP && d < DD) v = Wmp[(size_t)p * DD + d] * pmask[(size_t)p * DD + d];
    tile[r][tx] = v;
  }
  __syncthreads();
  for (int r = ty; r < 32; r += 8) {
    int d = d0 + r, p = p0 + tx;
    if (d < DD) Wt[(size_t)d * 512 + p] = tile[tx][r];
  }
}

// ---------- 11. GEMM1: partial[z][p][s] = Wt-slice^T x xt-slice ----------
__global__ __launch_bounds__(256) void k_gemm1(
    const float* __restrict__ xt, const float* __restrict__ Wt,
    float* __restrict__ partial) {
  __shared__ float As[SUB][64];   // [k][s]
  __shared__ float Ws[SUB][68];   // [k][p] padded
  int tid = threadIdx.x;
  int s0 = blockIdx.x * 64, p0 = blockIdx.y * 64, d0 = blockIdx.z * KCH;
  int ts = tid & 15, tp = tid >> 4;
  float acc[4][4];
  #pragma unroll
  for (int i = 0; i < 4; ++i)
    #pragma unroll
    for (int j = 0; j < 4; ++j) acc[i][j] = 0.f;

  for (int kt = 0; kt < KCH / SUB; ++kt) {
    int dd = d0 + kt * SUB;
    #pragma unroll
    for (int i = tid; i < SUB * 64; i += 256) {
      int r = i >> 6, c = i & 63;
      As[r][c] = xt[(size_t)(dd + r) * SS + s0 + c];
    }
    #pragma unroll
    for (int i = tid; i < SUB * 64; i += 256) {
      int r = i >> 6, c = i & 63;
      Ws[r][c] = Wt[(size_t)(dd + r) * 512 + p0 + c];
    }
    __syncthreads();
    #pragma unroll
    for (int kk = 0; kk < SUB; ++kk) {
      float4 a = *(const float4*)&As[kk][ts * 4];
      float4 b = *(const float4*)&Ws[kk][tp * 4];
      acc[0][0] += a.x * b.x; acc[0][1] += a.x * b.y; acc[0][2] += a.x * b.z; acc[0][3] += a.x * b.w;
      acc[1][0] += a.y * b.x; acc[1][1] += a.y * b.y; acc[1][2] += a.y * b.z; acc[1][3] += a.y * b.w;
      acc[2][0] += a.z * b.x; acc[2][1] += a.z * b.y; acc[2][2] += a.z * b.z; acc[2][3] += a.z * b.w;
      acc[3][0] += a.w * b.x; acc[3][1] += a.w * b.y; acc[3][2] += a.w * b.z; acc[3][3] += a.w * b.w;
    }
    __syncthreads();
  }
  float* dstp = partial + (size_t)blockIdx.z * 512 * 256;
  #pragma unroll
  for (int j = 0; j < 4; ++j) {
    int p = p0 + tp * 4 + j;
    float4 w; w.x = acc[0][j]; w.y = acc[1][j]; w.z = acc[2][j]; w.w = acc[3][j];
    *(float4*)&dstp[(size_t)p * 256 + s0 + ts * 4] = w;
  }
}

// ---------- 12. reduce partials + bias + relu ----------
__global__ __launch_bounds__(256) void k_reduce(
    const float* __restrict__ partial, const float* __restrict__ bmp,
    float* __restrict__ h1t) {
  int idx = blockIdx.x * 256 + threadIdx.x;
  if (idx >= PP * SS) return;
  float acc = bmp[idx >> 8];
  #pragma unroll
  for (int z = 0; z < ZSPLIT; ++z) acc += partial[(size_t)z * 512 * 256 + idx];
  h1t[idx] = fmaxf(acc, 0.0f);
}

// ---------- 13. h2t[ph][s] ----------
__global__ __launch_bounds__(256) void k_h2(
    const float* __restrict__ h1t, const float* __restrict__ Wph,
    const float* __restrict__ bph, float* __restrict__ h2t) {
  int ph = blockIdx.x;
  int s = threadIdx.x;
  float a0 = 0.f, a1 = 0.f, a2 = 0.f, a3 = 0.f;
  for (int p = 0; p < PP; p += 4) {
    a0 += h1t[(size_t)p * SS + s]       * Wph[ph * PP + p];
    a1 += h1t[(size_t)(p + 1) * SS + s] * Wph[ph * PP + p + 1];
    a2 += h1t[(size_t)(p + 2) * SS + s] * Wph[ph * PP + p + 2];
    a3 += h1t[(size_t)(p + 3) * SS + s] * Wph[ph * PP + p + 3];
  }
  h2t[(size_t)ph * SS + s] = fmaxf(a0 + a1 + a2 + a3 + bph[ph], 0.0f);
}

// ---------- 14. out[s,:] = softmax ----------
__global__ __launch_bounds__(256) void k_out(
    const float* __restrict__ h2t, const float* __restrict__ Wpo,
    const float* __restrict__ bpo, float* __restrict__ out) {
  int s = threadIdx.x;
  float o0 = bpo[0], o1 = bpo[1];
  for (int ph = 0; ph < PHH; ++ph) {
    float v = h2t[(size_t)ph * SS + s];
    o0 += v * Wpo[ph];
    o1 += v * Wpo[PHH + ph];
  }
  float mx = fmaxf(o0, o1);
  float e0 = __expf(o0 - mx), e1 = __expf(o1 - mx);
  float inv = 1.0f / (e0 + e1);
  out[2 * s] = e0 * inv;
  out[2 * s + 1] = e1 * inv;
}

extern "C" void kernel_launch(void* const* d_in, const int* in_sizes, int n_in,
                              void* d_out, int out_size, void* d_ws, size_t ws_size,
                              hipStream_t stream) {
  const float* lnc   = (const float*)d_in[0];
  const float* mi    = (const float*)d_in[1];
  const float* mdat  = (const float*)d_in[2];
  const int*   src   = (const int*)d_in[3];
  const int*   dst   = (const int*)d_in[4];
  const int*   dem   = (const int*)d_in[5];
  const float* attnl = (const float*)d_in[6];
  const float* attnr = (const float*)d_in[7];
  const float* bias0 = (const float*)d_in[8];
  const float* pmask = (const float*)d_in[9];
  const float* Wmp   = (const float*)d_in[10];
  const float* bmp   = (const float*)d_in[11];
  const float* Wph   = (const float*)d_in[12];
  const float* bph   = (const float*)d_in[13];
  const float* Wpo   = (const float*)d_in[14];
  const float* bpo   = (const float*)d_in[15];
  float* out = (float*)d_out;

  char* ws = (char*)d_ws;
  size_t off = 0;
  auto alloc = [&](size_t bytes) -> char* {
    char* p = ws + off;
    off += (bytes + 255) & ~(size_t)255;
    return p;
  };
  float*    mean    = (float*)alloc(SS * 4);
  float*    invstd  = (float*)alloc(SS * 4);
  float*    a1      = (float*)alloc(NN * 4);
  float*    a2      = (float*)alloc(NN * 4);
  float*    rowsum  = (float*)alloc(NN * 4);   // zero region start
  int*      counts  = (int*)alloc(NN * 4);     // zero region end
  int*      offs    = (int*)alloc((NN + 1) * 4);
  int*      cursor  = (int*)alloc(NN * 4);
  uint2*    csr     = (uint2*)alloc((size_t)EE * 8);
  ushort_t* a_rna   = (ushort_t*)alloc((size_t)NN * SS * 2);
  ushort_t* rna1    = (ushort_t*)alloc((size_t)NN * SS * 2);
  float*    xt      = (float*)alloc((size_t)DD * SS * 4);
  float*    Wt      = (float*)alloc((size_t)DD * 512 * 4);
  float*    partial = (float*)alloc((size_t)ZSPLIT * 512 * 256 * 4);
  float*    h1t     = (float*)alloc((size_t)PP * SS * 4);
  float*    h2t     = (float*)alloc((size_t)PHH * SS * 4);

  hipMemsetAsync(rowsum, 0, (size_t)((char*)offs - (char*)rowsum), stream);

  k_meanstd<<<SS, 256, 0, stream>>>(lnc, mi, mdat, mean, invstd);
  k_transpose<<<dim3(NN / 32, SS / 64), dim3(32, 8), 0, stream>>>(lnc, mi, mdat, mean, invstd, a_rna, rowsum);
  k_a1a2f<<<(NN + 255) / 256, 256, 0, stream>>>(rowsum, attnl, attnr, a1, a2);
  k_count<<<(EE + 255) / 256, 256, 0, stream>>>(dst, counts);
  k_scan<<<1, 1024, 0, stream>>>(counts, offs, cursor);
  k_fill<<<(EE + 255) / 256, 256, 0, stream>>>(src, dst, a1, a2, bias0, cursor, csr);
  k_znorm<<<NN / 4, 256, 0, stream>>>(offs, csr);
  k_agg<<<NN / 4, 256, 0, stream>>>(csr, offs, a_rna, rna1);
  k_pass2x<<<DD / 4, 256, 0, stream>>>(dem, offs, csr, a_rna, rna1, xt);
  k_maskw<<<dim3(16, (DD + 31) / 32), dim3(32, 8), 0, stream>>>(Wmp, pmask, Wt);
  k_gemm1<<<dim3(SS / 64, 8, ZSPLIT), 256, 0, stream>>>(xt, Wt, partial);
  k_reduce<<<(PP * SS + 255) / 256, 256, 0, stream>>>(partial, bmp, h1t);
  k_h2<<<PHH, SS, 0, stream>>>(h1t, Wph, bph, h2t);
  k_out<<<1, SS, 0, stream>>>(h2t, Wpo, bpo, out);
}

// Round 4
// 226.099 us; speedup vs baseline: 1.6139x; 1.0411x over previous
//
#include <hip/hip_runtime.h>

#define NN 20000
#define EE 640000
#define SS 256
#define DD 2000
#define PP 500
#define PHH 100
#define ZSPLIT 25
#define KCH 80
#define SUB 10

typedef unsigned short ushort_t;

__device__ __forceinline__ unsigned short f2bf(float f) {
  unsigned u = __float_as_uint(f);
  unsigned r = (u + 0x7FFFu + ((u >> 16) & 1u)) >> 16;  // RNE
  return (unsigned short)r;
}
__device__ __forceinline__ float lo16(unsigned u) { return __uint_as_float(u << 16); }
__device__ __forceinline__ float hi16(unsigned u) { return __uint_as_float(u & 0xFFFF0000u); }

// ---------- 0. zero small buffers (avoid rocclr fill path) ----------
__global__ __launch_bounds__(256) void k_zero(uint4* __restrict__ p, int n4) {
  int i = blockIdx.x * 256 + threadIdx.x;
  if (i < n4) { uint4 z; z.x = 0; z.y = 0; z.z = 0; z.w = 0; p[i] = z; }
}

// ---------- 1. per-sample mean / inv-std (f64 accumulation) ----------
__global__ __launch_bounds__(256) void k_meanstd(
    const float* __restrict__ lnc, const float* __restrict__ mi,
    const float* __restrict__ mdat, float* __restrict__ mean,
    float* __restrict__ invstd) {
  int s = blockIdx.x, tid = threadIdx.x;
  double sum = 0.0, ssq = 0.0;
  for (int i = tid; i < 8000; i += 256) { float v = lnc[s * 8000 + i];  sum += v; ssq += (double)v * v; }
  for (int i = tid; i < 2000; i += 256) { float v = mi[s * 2000 + i];   sum += v; ssq += (double)v * v; }
  for (int i = tid; i < 10000; i += 256){ float v = mdat[s * 10000 + i]; sum += v; ssq += (double)v * v; }
  __shared__ double sm[256], sq[256];
  sm[tid] = sum; sq[tid] = ssq; __syncthreads();
  for (int o = 128; o > 0; o >>= 1) {
    if (tid < o) { sm[tid] += sm[tid + o]; sq[tid] += sq[tid + o]; }
    __syncthreads();
  }
  if (tid == 0) {
    double mu = sm[0] / 20000.0;
    double var = (sq[0] - 20000.0 * mu * mu) / 19999.0;
    mean[s] = (float)mu;
    invstd[s] = (float)(1.0 / sqrt(var));
  }
}

// ---------- 2. normalize + transpose -> a_rna bf16 [N,S], slab row-sums ----------
__global__ __launch_bounds__(256) void k_transpose(
    const float* __restrict__ lnc, const float* __restrict__ mi,
    const float* __restrict__ mdat, const float* __restrict__ mean,
    const float* __restrict__ invstd, ushort_t* __restrict__ a_rna,
    float* __restrict__ rowsum4) {
  __shared__ float tile[64][33];  // [s][n]
  __shared__ float red[8][33];
  int nb = blockIdx.x * 32, sb = blockIdx.y * 64;
  int tx = threadIdx.x, ty = threadIdx.y;
  int n = nb + tx;
  const float* base; int w, c;
  if (n < 8000)       { base = lnc;  w = 8000;  c = n; }
  else if (n < 10000) { base = mi;   w = 2000;  c = n - 8000; }
  else                { base = mdat; w = 10000; c = n - 10000; }
  for (int r = ty; r < 64; r += 8) {
    int s = sb + r;
    tile[r][tx] = (base[(size_t)s * w + c] - mean[s]) * invstd[s];
  }
  __syncthreads();
  float ps = 0.f;
  for (int r = ty; r < 64; r += 8) ps += tile[r][tx];
  red[ty][tx] = ps;
  __syncthreads();
  if (ty == 0) {
    float t = 0.f;
    #pragma unroll
    for (int j = 0; j < 8; ++j) t += red[j][tx];
    rowsum4[(size_t)blockIdx.y * NN + nb + tx] = t;  // non-atomic slab partial
  }
  ushort2* out2 = (ushort2*)a_rna;
  for (int r2 = ty; r2 < 32; r2 += 8) {
    int nn = nb + r2;
    ushort2 v;
    v.x = f2bf(tile[2 * tx][r2]);
    v.y = f2bf(tile[2 * tx + 1][r2]);
    out2[(size_t)nn * 128 + (sb >> 1) + tx] = v;
  }
}

// ---------- 3. a1/a2 from slab partials ----------
__global__ __launch_bounds__(256) void k_a1a2f(
    const float* __restrict__ rowsum4, const float* __restrict__ attnl,
    const float* __restrict__ attnr, float* __restrict__ a1, float* __restrict__ a2) {
  int n = blockIdx.x * 256 + threadIdx.x;
  if (n >= NN) return;
  float t = rowsum4[n] + rowsum4[NN + n] + rowsum4[2 * NN + n] + rowsum4[3 * NN + n];
  a1[n] = attnl[n] * t;
  a2[n] = attnr[n] * t;
}

// ---------- 4. degree counts ----------
__global__ __launch_bounds__(256) void k_count(
    const int* __restrict__ dst, int* __restrict__ counts) {
  int e = blockIdx.x * 256 + threadIdx.x;
  if (e >= EE) return;
  atomicAdd(&counts[dst[e]], 1);
}

// ---------- 5. exclusive scan of counts (single block) ----------
__global__ __launch_bounds__(1024) void k_scan(
    const int* __restrict__ counts, int* __restrict__ offsets, int* __restrict__ cursor) {
  __shared__ int sums[1024];
  int t = threadIdx.x;
  int base = t * 20;
  int local[20];
  int s = 0;
  for (int i = 0; i < 20; ++i) {
    int idx = base + i;
    int c = (idx < NN) ? counts[idx] : 0;
    local[i] = s; s += c;
  }
  sums[t] = s; __syncthreads();
  for (int d = 1; d < 1024; d <<= 1) {
    int v = (t >= d) ? sums[t - d] : 0;
    __syncthreads();
    sums[t] += v;
    __syncthreads();
  }
  int prefix = (t > 0) ? sums[t - 1] : 0;
  for (int i = 0; i < 20; ++i) {
    int idx = base + i;
    if (idx < NN) { int o = prefix + local[i]; offsets[idx] = o; cursor[idx] = o; }
  }
  if (t == 1023) offsets[NN] = sums[1023];
}

// ---------- 6. CSR fill with raw (unnormalized) gate ----------
__device__ __forceinline__ float hc_gate(float l) {
  float sg = 1.0f / (1.0f + __expf(-l * 1.5151515151f));
  return fminf(fmaxf(fmaf(sg, 1.2f, -0.1f), 0.0f), 1.0f);
}

__global__ __launch_bounds__(256) void k_fill(
    const int* __restrict__ src, const int* __restrict__ dst,
    const float* __restrict__ a1, const float* __restrict__ a2,
    const float* __restrict__ bias0, int* __restrict__ cursor,
    uint2* __restrict__ csr) {
  int e = blockIdx.x * 256 + threadIdx.x;
  if (e >= EE) return;
  int d = dst[e], s = src[e];
  float a = hc_gate(a1[s] + a2[d] + bias0[0]);
  int slot = atomicAdd(&cursor[d], 1);
  uint2 rec; rec.x = (unsigned)s; rec.y = __float_as_uint(a);
  csr[slot] = rec;
}

// ---------- 7. pass-1 aggregation, fused z-normalize, 8-row pipeline ----------
__global__ __launch_bounds__(256) void k_agg(
    const uint2* __restrict__ csr, const int* __restrict__ offs,
    const ushort_t* __restrict__ in_bf, ushort_t* __restrict__ out_bf,
    float* __restrict__ zinv) {
  int wave = threadIdx.x >> 6, lane = threadIdx.x & 63;
  int half = lane >> 5, sl = lane & 31;
  int n = blockIdx.x * 4 + wave;
  int beg = __builtin_amdgcn_readfirstlane(offs[n]);
  int end = __builtin_amdgcn_readfirstlane(offs[n + 1]);
  // z prescan over this node's segment (L2-hot)
  float zp = 0.f;
  for (int i = beg + lane; i < end; i += 64) zp += __uint_as_float(csr[i].y);
  #pragma unroll
  for (int o = 1; o < 64; o <<= 1) zp += __shfl_xor(zp, o, 64);
  float inv = (zp > 0.f) ? 1.0f / zp : 0.0f;
  if (lane == 0) zinv[n] = inv;

  const uint4* in4 = (const uint4*)in_bf;  // 8 bf16 per uint4, row = 32 uint4
  float acc[8] = {0.f, 0.f, 0.f, 0.f, 0.f, 0.f, 0.f, 0.f};
  int i = beg;
  for (; i + 7 < end; i += 8) {
    uint2 rA = csr[i + half];
    uint2 rB = csr[i + 2 + half];
    uint2 rC = csr[i + 4 + half];
    uint2 rD = csr[i + 6 + half];
    uint4 vA = in4[(size_t)rA.x * 32 + sl];
    uint4 vB = in4[(size_t)rB.x * 32 + sl];
    uint4 vC = in4[(size_t)rC.x * 32 + sl];
    uint4 vD = in4[(size_t)rD.x * 32 + sl];
    float gA = __uint_as_float(rA.y) * inv, gB = __uint_as_float(rB.y) * inv;
    float gC = __uint_as_float(rC.y) * inv, gD = __uint_as_float(rD.y) * inv;
    acc[0] += gA * lo16(vA.x) + gB * lo16(vB.x) + gC * lo16(vC.x) + gD * lo16(vD.x);
    acc[1] += gA * hi16(vA.x) + gB * hi16(vB.x) + gC * hi16(vC.x) + gD * hi16(vD.x);
    acc[2] += gA * lo16(vA.y) + gB * lo16(vB.y) + gC * lo16(vC.y) + gD * lo16(vD.y);
    acc[3] += gA * hi16(vA.y) + gB * hi16(vB.y) + gC * hi16(vC.y) + gD * hi16(vD.y);
    acc[4] += gA * lo16(vA.z) + gB * lo16(vB.z) + gC * lo16(vC.z) + gD * lo16(vD.z);
    acc[5] += gA * hi16(vA.z) + gB * hi16(vB.z) + gC * hi16(vC.z) + gD * hi16(vD.z);
    acc[6] += gA * lo16(vA.w) + gB * lo16(vB.w) + gC * lo16(vC.w) + gD * lo16(vD.w);
    acc[7] += gA * hi16(vA.w) + gB * hi16(vB.w) + gC * hi16(vC.w) + gD * hi16(vD.w);
  }
  for (; i + 3 < end; i += 4) {
    uint2 rA = csr[i + half];
    uint2 rB = csr[i + 2 + half];
    uint4 vA = in4[(size_t)rA.x * 32 + sl];
    uint4 vB = in4[(size_t)rB.x * 32 + sl];
    float gA = __uint_as_float(rA.y) * inv, gB = __uint_as_float(rB.y) * inv;
    acc[0] += gA * lo16(vA.x) + gB * lo16(vB.x);
    acc[1] += gA * hi16(vA.x) + gB * hi16(vB.x);
    acc[2] += gA * lo16(vA.y) + gB * lo16(vB.y);
    acc[3] += gA * hi16(vA.y) + gB * hi16(vB.y);
    acc[4] += gA * lo16(vA.z) + gB * lo16(vB.z);
    acc[5] += gA * hi16(vA.z) + gB * hi16(vB.z);
    acc[6] += gA * lo16(vA.w) + gB * lo16(vB.w);
    acc[7] += gA * hi16(vA.w) + gB * hi16(vB.w);
  }
  for (; i + 1 < end; i += 2) {
    uint2 rA = csr[i + half];
    uint4 vA = in4[(size_t)rA.x * 32 + sl];
    float gA = __uint_as_float(rA.y) * inv;
    acc[0] += gA * lo16(vA.x); acc[1] += gA * hi16(vA.x);
    acc[2] += gA * lo16(vA.y); acc[3] += gA * hi16(vA.y);
    acc[4] += gA * lo16(vA.z); acc[5] += gA * hi16(vA.z);
    acc[6] += gA * lo16(vA.w); acc[7] += gA * hi16(vA.w);
  }
  if (i < end && half == 0) {
    uint2 rA = csr[i];
    uint4 vA = in4[(size_t)rA.x * 32 + sl];
    float gA = __uint_as_float(rA.y) * inv;
    acc[0] += gA * lo16(vA.x); acc[1] += gA * hi16(vA.x);
    acc[2] += gA * lo16(vA.y); acc[3] += gA * hi16(vA.y);
    acc[4] += gA * lo16(vA.z); acc[5] += gA * hi16(vA.z);
    acc[6] += gA * lo16(vA.w); acc[7] += gA * hi16(vA.w);
  }
  #pragma unroll
  for (int j = 0; j < 8; ++j) acc[j] += __shfl_xor(acc[j], 32, 64);
  if (half == 0) {
    uint4 w;
    w.x = (unsigned)f2bf(acc[0]) | ((unsigned)f2bf(acc[1]) << 16);
    w.y = (unsigned)f2bf(acc[2]) | ((unsigned)f2bf(acc[3]) << 16);
    w.z = (unsigned)f2bf(acc[4]) | ((unsigned)f2bf(acc[5]) << 16);
    w.w = (unsigned)f2bf(acc[6]) | ((unsigned)f2bf(acc[7]) << 16);
    ((uint4*)out_bf)[(size_t)n * 32 + sl] = w;
  }
}

// ---------- 8. fused pass-2 + x build: xt[d][s] f32 ----------
__global__ __launch_bounds__(256) void k_pass2x(
    const int* __restrict__ dem, const int* __restrict__ offs,
    const uint2* __restrict__ csr, const ushort_t* __restrict__ a_rna,
    const ushort_t* __restrict__ rna1, const float* __restrict__ zinv,
    float* __restrict__ xt) {
  int wave = threadIdx.x >> 6, lane = threadIdx.x & 63;
  int half = lane >> 5, sl = lane & 31;
  int d = blockIdx.x * 4 + wave;
  int nd = dem[d];
  const uint4* ar = (const uint4*)a_rna;
  const uint4* r1 = (const uint4*)rna1;
  int beg = __builtin_amdgcn_readfirstlane(offs[nd]);
  int end = __builtin_amdgcn_readfirstlane(offs[nd + 1]);
  float inv = zinv[nd];
  float acc[8] = {0.f, 0.f, 0.f, 0.f, 0.f, 0.f, 0.f, 0.f};
  int i = beg;
  for (; i + 3 < end; i += 4) {
    uint2 rA = csr[i + half];
    uint2 rB = csr[i + 2 + half];
    uint4 vA = r1[(size_t)rA.x * 32 + sl];
    uint4 vB = r1[(size_t)rB.x * 32 + sl];
    float gA = __uint_as_float(rA.y) * inv, gB = __uint_as_float(rB.y) * inv;
    acc[0] += gA * lo16(vA.x) + gB * lo16(vB.x);
    acc[1] += gA * hi16(vA.x) + gB * hi16(vB.x);
    acc[2] += gA * lo16(vA.y) + gB * lo16(vB.y);
    acc[3] += gA * hi16(vA.y) + gB * hi16(vB.y);
    acc[4] += gA * lo16(vA.z) + gB * lo16(vB.z);
    acc[5] += gA * hi16(vA.z) + gB * hi16(vB.z);
    acc[6] += gA * lo16(vA.w) + gB * lo16(vB.w);
    acc[7] += gA * hi16(vA.w) + gB * hi16(vB.w);
  }
  for (; i + 1 < end; i += 2) {
    uint2 rA = csr[i + half];
    uint4 vA = r1[(size_t)rA.x * 32 + sl];
    float gA = __uint_as_float(rA.y) * inv;
    acc[0] += gA * lo16(vA.x); acc[1] += gA * hi16(vA.x);
    acc[2] += gA * lo16(vA.y); acc[3] += gA * hi16(vA.y);
    acc[4] += gA * lo16(vA.z); acc[5] += gA * hi16(vA.z);
    acc[6] += gA * lo16(vA.w); acc[7] += gA * hi16(vA.w);
  }
  if (i < end && half == 0) {
    uint2 rA = csr[i];
    uint4 vA = r1[(size_t)rA.x * 32 + sl];
    float gA = __uint_as_float(rA.y) * inv;
    acc[0] += gA * lo16(vA.x); acc[1] += gA * hi16(vA.x);
    acc[2] += gA * lo16(vA.y); acc[3] += gA * hi16(vA.y);
    acc[4] += gA * lo16(vA.z); acc[5] += gA * hi16(vA.z);
    acc[6] += gA * lo16(vA.w); acc[7] += gA * hi16(vA.w);
  }
  #pragma unroll
  for (int j = 0; j < 8; ++j) acc[j] += __shfl_xor(acc[j], 32, 64);
  if (half == 0) {
    uint4 va = ar[(size_t)nd * 32 + sl];
    uint4 vb = r1[(size_t)nd * 32 + sl];
    acc[0] += lo16(va.x) + lo16(vb.x); acc[1] += hi16(va.x) + hi16(vb.x);
    acc[2] += lo16(va.y) + lo16(vb.y); acc[3] += hi16(va.y) + hi16(vb.y);
    acc[4] += lo16(va.z) + lo16(vb.z); acc[5] += hi16(va.z) + hi16(vb.z);
    acc[6] += lo16(va.w) + lo16(vb.w); acc[7] += hi16(va.w) + hi16(vb.w);
    float4* xo = (float4*)&xt[(size_t)d * SS + sl * 8];
    float4 w0; w0.x = acc[0]; w0.y = acc[1]; w0.z = acc[2]; w0.w = acc[3];
    float4 w1; w1.x = acc[4]; w1.y = acc[5]; w1.z = acc[6]; w1.w = acc[7];
    xo[0] = w0; xo[1] = w1;
  }
}

// ---------- 9. masked weight transpose: Wt[d][p] (p zero-padded to 512) ----------
__global__ __launch_bounds__(256) void k_maskw(
    const float* __restrict__ Wmp, const float* __restrict__ pmask,
    float* __restrict__ Wt) {
  __shared__ float tile[32][33];
  int p0 = blockIdx.x * 32, d0 = blockIdx.y * 32;
  int tx = threadIdx.x, ty = threadIdx.y;
  for (int r = ty; r < 32; r += 8) {
    int p = p0 + r, d = d0 + tx;
    float v = 0.f;
    if (p < PP && d < DD) v = Wmp[(size_t)p * DD + d] * pmask[(size_t)p * DD + d];
    tile[r][tx] = v;
  }
  __syncthreads();
  for (int r = ty; r < 32; r += 8) {
    int d = d0 + r, p = p0 + tx;
    if (d < DD) Wt[(size_t)d * 512 + p] = tile[tx][r];
  }
}

// ---------- 10. GEMM1: partial[z][p][s] = Wt-slice^T x xt-slice ----------
__global__ __launch_bounds__(256) void k_gemm1(
    const float* __restrict__ xt, const float* __restrict__ Wt,
    float* __restrict__ partial) {
  __shared__ float As[SUB][64];   // [k][s]
  __shared__ float Ws[SUB][68];   // [k][p] padded
  int tid = threadIdx.x;
  int s0 = blockIdx.x * 64, p0 = blockIdx.y * 64, d0 = blockIdx.z * KCH;
  int ts = tid & 15, tp = tid >> 4;
  float acc[4][4];
  #pragma unroll
  for (int i = 0; i < 4; ++i)
    #pragma unroll
    for (int j = 0; j < 4; ++j) acc[i][j] = 0.f;

  for (int kt = 0; kt < KCH / SUB; ++kt) {
    int dd = d0 + kt * SUB;
    #pragma unroll
    for (int i = tid; i < SUB * 64; i += 256) {
      int r = i >> 6, c = i & 63;
      As[r][c] = xt[(size_t)(dd + r) * SS + s0 + c];
    }
    #pragma unroll
    for (int i = tid; i < SUB * 64; i += 256) {
      int r = i >> 6, c = i & 63;
      Ws[r][c] = Wt[(size_t)(dd + r) * 512 + p0 + c];
    }
    __syncthreads();
    #pragma unroll
    for (int kk = 0; kk < SUB; ++kk) {
      float4 a = *(const float4*)&As[kk][ts * 4];
      float4 b = *(const float4*)&Ws[kk][tp * 4];
      acc[0][0] += a.x * b.x; acc[0][1] += a.x * b.y; acc[0][2] += a.x * b.z; acc[0][3] += a.x * b.w;
      acc[1][0] += a.y * b.x; acc[1][1] += a.y * b.y; acc[1][2] += a.y * b.z; acc[1][3] += a.y * b.w;
      acc[2][0] += a.z * b.x; acc[2][1] += a.z * b.y; acc[2][2] += a.z * b.z; acc[2][3] += a.z * b.w;
      acc[3][0] += a.w * b.x; acc[3][1] += a.w * b.y; acc[3][2] += a.w * b.z; acc[3][3] += a.w * b.w;
    }
    __syncthreads();
  }
  float* dstp = partial + (size_t)blockIdx.z * 512 * 256;
  #pragma unroll
  for (int j = 0; j < 4; ++j) {
    int p = p0 + tp * 4 + j;
    float4 w; w.x = acc[0][j]; w.y = acc[1][j]; w.z = acc[2][j]; w.w = acc[3][j];
    *(float4*)&dstp[(size_t)p * 256 + s0 + ts * 4] = w;
  }
}

// ---------- 11. reduce partials + bias + relu ----------
__global__ __launch_bounds__(256) void k_reduce(
    const float* __restrict__ partial, const float* __restrict__ bmp,
    float* __restrict__ h1t) {
  int idx = blockIdx.x * 256 + threadIdx.x;
  if (idx >= PP * SS) return;
  float acc = bmp[idx >> 8];
  #pragma unroll
  for (int z = 0; z < ZSPLIT; ++z) acc += partial[(size_t)z * 512 * 256 + idx];
  h1t[idx] = fmaxf(acc, 0.0f);
}

// ---------- 12. h2t[ph][s]: one wave per (ph, 64-s block), 10-way ILP ----------
__global__ __launch_bounds__(64) void k_h2(
    const float* __restrict__ h1t, const float* __restrict__ Wph,
    const float* __restrict__ bph, float* __restrict__ h2t) {
  int ph = blockIdx.x;
  int s = blockIdx.y * 64 + threadIdx.x;
  const float* w = &Wph[(size_t)ph * PP];
  float acc[10];
  #pragma unroll
  for (int j = 0; j < 10; ++j) acc[j] = 0.f;
  for (int k = 0; k < 50; ++k) {
    int p = k * 10;
    #pragma unroll
    for (int j = 0; j < 10; ++j)
      acc[j] = fmaf(h1t[(size_t)(p + j) * SS + s], w[p + j], acc[j]);
  }
  float t = ((acc[0] + acc[1]) + (acc[2] + acc[3])) + ((acc[4] + acc[5]) + (acc[6] + acc[7])) + (acc[8] + acc[9]);
  h2t[(size_t)ph * SS + s] = fmaxf(t + bph[ph], 0.0f);
}

// ---------- 13. out[s,:] = softmax ----------
__global__ __launch_bounds__(256) void k_out(
    const float* __restrict__ h2t, const float* __restrict__ Wpo,
    const float* __restrict__ bpo, float* __restrict__ out) {
  int s = threadIdx.x;
  float o0 = bpo[0], o1 = bpo[1];
  for (int ph = 0; ph < PHH; ++ph) {
    float v = h2t[(size_t)ph * SS + s];
    o0 += v * Wpo[ph];
    o1 += v * Wpo[PHH + ph];
  }
  float mx = fmaxf(o0, o1);
  float e0 = __expf(o0 - mx), e1 = __expf(o1 - mx);
  float inv = 1.0f / (e0 + e1);
  out[2 * s] = e0 * inv;
  out[2 * s + 1] = e1 * inv;
}

extern "C" void kernel_launch(void* const* d_in, const int* in_sizes, int n_in,
                              void* d_out, int out_size, void* d_ws, size_t ws_size,
                              hipStream_t stream) {
  const float* lnc   = (const float*)d_in[0];
  const float* mi    = (const float*)d_in[1];
  const float* mdat  = (const float*)d_in[2];
  const int*   src   = (const int*)d_in[3];
  const int*   dst   = (const int*)d_in[4];
  const int*   dem   = (const int*)d_in[5];
  const float* attnl = (const float*)d_in[6];
  const float* attnr = (const float*)d_in[7];
  const float* bias0 = (const float*)d_in[8];
  const float* pmask = (const float*)d_in[9];
  const float* Wmp   = (const float*)d_in[10];
  const float* bmp   = (const float*)d_in[11];
  const float* Wph   = (const float*)d_in[12];
  const float* bph   = (const float*)d_in[13];
  const float* Wpo   = (const float*)d_in[14];
  const float* bpo   = (const float*)d_in[15];
  float* out = (float*)d_out;

  char* ws = (char*)d_ws;
  size_t off = 0;
  auto alloc = [&](size_t bytes) -> char* {
    char* p = ws + off;
    off += (bytes + 255) & ~(size_t)255;
    return p;
  };
  float*    mean    = (float*)alloc(SS * 4);
  float*    invstd  = (float*)alloc(SS * 4);
  float*    a1      = (float*)alloc(NN * 4);
  float*    a2      = (float*)alloc(NN * 4);
  float*    rowsum4 = (float*)alloc((size_t)4 * NN * 4);
  float*    zinv    = (float*)alloc(NN * 4);
  int*      counts  = (int*)alloc(NN * 4);
  int*      offs    = (int*)alloc((NN + 1) * 4);
  int*      cursor  = (int*)alloc(NN * 4);
  uint2*    csr     = (uint2*)alloc((size_t)EE * 8);
  ushort_t* a_rna   = (ushort_t*)alloc((size_t)NN * SS * 2);
  ushort_t* rna1    = (ushort_t*)alloc((size_t)NN * SS * 2);
  float*    xt      = (float*)alloc((size_t)DD * SS * 4);
  float*    Wt      = (float*)alloc((size_t)DD * 512 * 4);
  float*    partial = (float*)alloc((size_t)ZSPLIT * 512 * 256 * 4);
  float*    h1t     = (float*)alloc((size_t)PP * SS * 4);
  float*    h2t     = (float*)alloc((size_t)PHH * SS * 4);

  k_zero<<<(NN / 4 + 255) / 256, 256, 0, stream>>>((uint4*)counts, NN / 4);
  k_meanstd<<<SS, 256, 0, stream>>>(lnc, mi, mdat, mean, invstd);
  k_transpose<<<dim3(NN / 32, SS / 64), dim3(32, 8), 0, stream>>>(lnc, mi, mdat, mean, invstd, a_rna, rowsum4);
  k_a1a2f<<<(NN + 255) / 256, 256, 0, stream>>>(rowsum4, attnl, attnr, a1, a2);
  k_count<<<(EE + 255) / 256, 256, 0, stream>>>(dst, counts);
  k_scan<<<1, 1024, 0, stream>>>(counts, offs, cursor);
  k_fill<<<(EE + 255) / 256, 256, 0, stream>>>(src, dst, a1, a2, bias0, cursor, csr);
  k_agg<<<NN / 4, 256, 0, stream>>>(csr, offs, a_rna, rna1, zinv);
  k_pass2x<<<DD / 4, 256, 0, stream>>>(dem, offs, csr, a_rna, rna1, zinv, xt);
  k_maskw<<<dim3(16, (DD + 31) / 32), dim3(32, 8), 0, stream>>>(Wmp, pmask, Wt);
  k_gemm1<<<dim3(SS / 64, 8, ZSPLIT), 256, 0, stream>>>(xt, Wt, partial);
  k_reduce<<<(PP * SS + 255) / 256, 256, 0, stream>>>(partial, bmp, h1t);
  k_h2<<<dim3(PHH, SS / 64), 64, 0, stream>>>(h1t, Wph, bph, h2t);
  k_out<<<1, SS, 0, stream>>>(h2t, Wpo, bpo, out);
}

// Round 5
// 215.368 us; speedup vs baseline: 1.6943x; 1.0498x over previous
//
#include <hip/hip_runtime.h>

#define NN 20000
#define EE 640000
#define SS 256
#define DD 2000
#define PP 500
#define PHH 100
#define ZSPLIT 25
#define KCH 80
#define SUB 10

typedef unsigned short ushort_t;

__device__ __forceinline__ unsigned short f2bf(float f) {
  unsigned u = __float_as_uint(f);
  unsigned r = (u + 0x7FFFu + ((u >> 16) & 1u)) >> 16;  // RNE
  return (unsigned short)r;
}
__device__ __forceinline__ float lo16(unsigned u) { return __uint_as_float(u << 16); }
__device__ __forceinline__ float hi16(unsigned u) { return __uint_as_float(u & 0xFFFF0000u); }

// ---------- 1. per-sample mean / inv-std (f64 accumulation) ----------
__global__ __launch_bounds__(256) void k_meanstd(
    const float* __restrict__ lnc, const float* __restrict__ mi,
    const float* __restrict__ mdat, float* __restrict__ mean,
    float* __restrict__ invstd) {
  int s = blockIdx.x, tid = threadIdx.x;
  double sum = 0.0, ssq = 0.0;
  for (int i = tid; i < 8000; i += 256) { float v = lnc[s * 8000 + i];  sum += v; ssq += (double)v * v; }
  for (int i = tid; i < 2000; i += 256) { float v = mi[s * 2000 + i];   sum += v; ssq += (double)v * v; }
  for (int i = tid; i < 10000; i += 256){ float v = mdat[s * 10000 + i]; sum += v; ssq += (double)v * v; }
  __shared__ double sm[256], sq[256];
  sm[tid] = sum; sq[tid] = ssq; __syncthreads();
  for (int o = 128; o > 0; o >>= 1) {
    if (tid < o) { sm[tid] += sm[tid + o]; sq[tid] += sq[tid + o]; }
    __syncthreads();
  }
  if (tid == 0) {
    double mu = sm[0] / 20000.0;
    double var = (sq[0] - 20000.0 * mu * mu) / 19999.0;
    mean[s] = (float)mu;
    invstd[s] = (float)(1.0 / sqrt(var));
  }
}

// ---------- 2. fused: transpose(+rowsum) | maskw | zero-counts ----------
// blocks [0,2500): normalize+transpose -> a_rna bf16 [N,S] + slab row-sums
// blocks [2500,3508): Wt[d][p] = (Wmp*mask)^T zero-padded to p<512
// blocks [3508,3528): zero counts
__global__ __launch_bounds__(256) void k_prep(
    const float* __restrict__ lnc, const float* __restrict__ mi,
    const float* __restrict__ mdat, const float* __restrict__ mean,
    const float* __restrict__ invstd, ushort_t* __restrict__ a_rna,
    float* __restrict__ rowsum4, const float* __restrict__ Wmp,
    const float* __restrict__ pmask, float* __restrict__ Wt,
    int* __restrict__ counts) {
  int b = blockIdx.x;
  int tx = threadIdx.x, ty = threadIdx.y;
  if (b < 2500) {
    __shared__ float tile[64][33];  // [s][n]
    __shared__ float red[8][33];
    int nb = (b % 625) * 32, sb = (b / 625) * 64;
    int n = nb + tx;
    const float* base; int w, c;
    if (n < 8000)       { base = lnc;  w = 8000;  c = n; }
    else if (n < 10000) { base = mi;   w = 2000;  c = n - 8000; }
    else                { base = mdat; w = 10000; c = n - 10000; }
    for (int r = ty; r < 64; r += 8) {
      int s = sb + r;
      tile[r][tx] = (base[(size_t)s * w + c] - mean[s]) * invstd[s];
    }
    __syncthreads();
    float ps = 0.f;
    for (int r = ty; r < 64; r += 8) ps += tile[r][tx];
    red[ty][tx] = ps;
    __syncthreads();
    if (ty == 0) {
      float t = 0.f;
      #pragma unroll
      for (int j = 0; j < 8; ++j) t += red[j][tx];
      rowsum4[(size_t)(sb >> 6) * NN + nb + tx] = t;
    }
    ushort2* out2 = (ushort2*)a_rna;
    for (int r2 = ty; r2 < 32; r2 += 8) {
      int nn = nb + r2;
      ushort2 v;
      v.x = f2bf(tile[2 * tx][r2]);
      v.y = f2bf(tile[2 * tx + 1][r2]);
      out2[(size_t)nn * 128 + (sb >> 1) + tx] = v;
    }
  } else if (b < 3508) {
    __shared__ float tile[32][33];
    int b2 = b - 2500;
    int p0 = (b2 & 15) * 32, d0 = (b2 >> 4) * 32;
    for (int r = ty; r < 32; r += 8) {
      int p = p0 + r, d = d0 + tx;
      float v = 0.f;
      if (p < PP && d < DD) v = Wmp[(size_t)p * DD + d] * pmask[(size_t)p * DD + d];
      tile[r][tx] = v;
    }
    __syncthreads();
    for (int r = ty; r < 32; r += 8) {
      int d = d0 + r, p = p0 + tx;
      if (d < DD) Wt[(size_t)d * 512 + p] = tile[tx][r];
    }
  } else {
    int b3 = b - 3508;
    int idx = b3 * 256 + ty * 32 + tx;
    if (idx < NN / 4) {
      uint4 z; z.x = 0; z.y = 0; z.z = 0; z.w = 0;
      ((uint4*)counts)[idx] = z;
    }
  }
}

// ---------- 3. fused: degree counts | a1/a2 finalize ----------
__global__ __launch_bounds__(256) void k_count2(
    const int* __restrict__ dst, int* __restrict__ counts,
    const float* __restrict__ rowsum4, const float* __restrict__ attnl,
    const float* __restrict__ attnr, float* __restrict__ a1, float* __restrict__ a2) {
  int b = blockIdx.x;
  if (b < 2500) {
    int e = b * 256 + threadIdx.x;
    if (e < EE) atomicAdd(&counts[dst[e]], 1);
  } else {
    int n = (b - 2500) * 256 + threadIdx.x;
    if (n < NN) {
      float t = rowsum4[n] + rowsum4[NN + n] + rowsum4[2 * NN + n] + rowsum4[3 * NN + n];
      a1[n] = attnl[n] * t;
      a2[n] = attnr[n] * t;
    }
  }
}

// ---------- 4. exclusive scan of counts (single block) ----------
__global__ __launch_bounds__(1024) void k_scan(
    const int* __restrict__ counts, int* __restrict__ offsets, int* __restrict__ cursor) {
  __shared__ int sums[1024];
  int t = threadIdx.x;
  int base = t * 20;
  int local[20];
  int s = 0;
  for (int i = 0; i < 20; ++i) {
    int idx = base + i;
    int c = (idx < NN) ? counts[idx] : 0;
    local[i] = s; s += c;
  }
  sums[t] = s; __syncthreads();
  for (int d = 1; d < 1024; d <<= 1) {
    int v = (t >= d) ? sums[t - d] : 0;
    __syncthreads();
    sums[t] += v;
    __syncthreads();
  }
  int prefix = (t > 0) ? sums[t - 1] : 0;
  for (int i = 0; i < 20; ++i) {
    int idx = base + i;
    if (idx < NN) { int o = prefix + local[i]; offsets[idx] = o; cursor[idx] = o; }
  }
  if (t == 1023) offsets[NN] = sums[1023];
}

// ---------- 5. CSR fill with raw (unnormalized) gate ----------
__device__ __forceinline__ float hc_gate(float l) {
  float sg = 1.0f / (1.0f + __expf(-l * 1.5151515151f));
  return fminf(fmaxf(fmaf(sg, 1.2f, -0.1f), 0.0f), 1.0f);
}

__global__ __launch_bounds__(256) void k_fill(
    const int* __restrict__ src, const int* __restrict__ dst,
    const float* __restrict__ a1, const float* __restrict__ a2,
    const float* __restrict__ bias0, int* __restrict__ cursor,
    uint2* __restrict__ csr) {
  int e = blockIdx.x * 256 + threadIdx.x;
  if (e >= EE) return;
  int d = dst[e], s = src[e];
  float a = hc_gate(a1[s] + a2[d] + bias0[0]);
  int slot = atomicAdd(&cursor[d], 1);
  uint2 rec; rec.x = (unsigned)s; rec.y = __float_as_uint(a);
  csr[slot] = rec;
}

// ---------- 6. pass-1 aggregation, fused z-normalize, 16-deep pipeline ----------
__global__ __launch_bounds__(256) void k_agg(
    const uint2* __restrict__ csr, const int* __restrict__ offs,
    const ushort_t* __restrict__ in_bf, ushort_t* __restrict__ out_bf,
    float* __restrict__ zinv) {
  int wave = threadIdx.x >> 6, lane = threadIdx.x & 63;
  int half = lane >> 5, sl = lane & 31;
  int n = blockIdx.x * 4 + wave;
  int beg = __builtin_amdgcn_readfirstlane(offs[n]);
  int end = __builtin_amdgcn_readfirstlane(offs[n + 1]);
  // z prescan over this node's segment (L2-hot)
  float zp = 0.f;
  for (int i = beg + lane; i < end; i += 64) zp += __uint_as_float(csr[i].y);
  #pragma unroll
  for (int o = 1; o < 64; o <<= 1) zp += __shfl_xor(zp, o, 64);
  float inv = (zp > 0.f) ? 1.0f / zp : 0.0f;
  if (lane == 0) zinv[n] = inv;

  const uint4* in4 = (const uint4*)in_bf;  // 8 bf16 per uint4, row = 32 uint4
  float acc[8] = {0.f, 0.f, 0.f, 0.f, 0.f, 0.f, 0.f, 0.f};
  int i = beg;
  for (; i + 15 < end; i += 16) {
    uint2 r[8]; uint4 v[8];
    #pragma unroll
    for (int j = 0; j < 8; ++j) r[j] = csr[i + 2 * j + half];
    #pragma unroll
    for (int j = 0; j < 8; ++j) v[j] = in4[(size_t)r[j].x * 32 + sl];
    #pragma unroll
    for (int j = 0; j < 8; ++j) {
      float g = __uint_as_float(r[j].y) * inv;
      acc[0] += g * lo16(v[j].x); acc[1] += g * hi16(v[j].x);
      acc[2] += g * lo16(v[j].y); acc[3] += g * hi16(v[j].y);
      acc[4] += g * lo16(v[j].z); acc[5] += g * hi16(v[j].z);
      acc[6] += g * lo16(v[j].w); acc[7] += g * hi16(v[j].w);
    }
  }
  for (; i + 3 < end; i += 4) {
    uint2 rA = csr[i + half];
    uint2 rB = csr[i + 2 + half];
    uint4 vA = in4[(size_t)rA.x * 32 + sl];
    uint4 vB = in4[(size_t)rB.x * 32 + sl];
    float gA = __uint_as_float(rA.y) * inv, gB = __uint_as_float(rB.y) * inv;
    acc[0] += gA * lo16(vA.x) + gB * lo16(vB.x);
    acc[1] += gA * hi16(vA.x) + gB * hi16(vB.x);
    acc[2] += gA * lo16(vA.y) + gB * lo16(vB.y);
    acc[3] += gA * hi16(vA.y) + gB * hi16(vB.y);
    acc[4] += gA * lo16(vA.z) + gB * lo16(vB.z);
    acc[5] += gA * hi16(vA.z) + gB * hi16(vB.z);
    acc[6] += gA * lo16(vA.w) + gB * lo16(vB.w);
    acc[7] += gA * hi16(vA.w) + gB * hi16(vB.w);
  }
  for (; i + 1 < end; i += 2) {
    uint2 rA = csr[i + half];
    uint4 vA = in4[(size_t)rA.x * 32 + sl];
    float gA = __uint_as_float(rA.y) * inv;
    acc[0] += gA * lo16(vA.x); acc[1] += gA * hi16(vA.x);
    acc[2] += gA * lo16(vA.y); acc[3] += gA * hi16(vA.y);
    acc[4] += gA * lo16(vA.z); acc[5] += gA * hi16(vA.z);
    acc[6] += gA * lo16(vA.w); acc[7] += gA * hi16(vA.w);
  }
  if (i < end && half == 0) {
    uint2 rA = csr[i];
    uint4 vA = in4[(size_t)rA.x * 32 + sl];
    float gA = __uint_as_float(rA.y) * inv;
    acc[0] += gA * lo16(vA.x); acc[1] += gA * hi16(vA.x);
    acc[2] += gA * lo16(vA.y); acc[3] += gA * hi16(vA.y);
    acc[4] += gA * lo16(vA.z); acc[5] += gA * hi16(vA.z);
    acc[6] += gA * lo16(vA.w); acc[7] += gA * hi16(vA.w);
  }
  #pragma unroll
  for (int j = 0; j < 8; ++j) acc[j] += __shfl_xor(acc[j], 32, 64);
  if (half == 0) {
    uint4 w;
    w.x = (unsigned)f2bf(acc[0]) | ((unsigned)f2bf(acc[1]) << 16);
    w.y = (unsigned)f2bf(acc[2]) | ((unsigned)f2bf(acc[3]) << 16);
    w.z = (unsigned)f2bf(acc[4]) | ((unsigned)f2bf(acc[5]) << 16);
    w.w = (unsigned)f2bf(acc[6]) | ((unsigned)f2bf(acc[7]) << 16);
    ((uint4*)out_bf)[(size_t)n * 32 + sl] = w;
  }
}

// ---------- 7. fused pass-2 + x build: xt[d][s] f32 ----------
__global__ __launch_bounds__(256) void k_pass2x(
    const int* __restrict__ dem, const int* __restrict__ offs,
    const uint2* __restrict__ csr, const ushort_t* __restrict__ a_rna,
    const ushort_t* __restrict__ rna1, const float* __restrict__ zinv,
    float* __restrict__ xt) {
  int wave = threadIdx.x >> 6, lane = threadIdx.x & 63;
  int half = lane >> 5, sl = lane & 31;
  int d = blockIdx.x * 4 + wave;
  int nd = dem[d];
  const uint4* ar = (const uint4*)a_rna;
  const uint4* r1 = (const uint4*)rna1;
  int beg = __builtin_amdgcn_readfirstlane(offs[nd]);
  int end = __builtin_amdgcn_readfirstlane(offs[nd + 1]);
  float inv = zinv[nd];
  float acc[8] = {0.f, 0.f, 0.f, 0.f, 0.f, 0.f, 0.f, 0.f};
  int i = beg;
  for (; i + 3 < end; i += 4) {
    uint2 rA = csr[i + half];
    uint2 rB = csr[i + 2 + half];
    uint4 vA = r1[(size_t)rA.x * 32 + sl];
    uint4 vB = r1[(size_t)rB.x * 32 + sl];
    float gA = __uint_as_float(rA.y) * inv, gB = __uint_as_float(rB.y) * inv;
    acc[0] += gA * lo16(vA.x) + gB * lo16(vB.x);
    acc[1] += gA * hi16(vA.x) + gB * hi16(vB.x);
    acc[2] += gA * lo16(vA.y) + gB * lo16(vB.y);
    acc[3] += gA * hi16(vA.y) + gB * hi16(vB.y);
    acc[4] += gA * lo16(vA.z) + gB * lo16(vB.z);
    acc[5] += gA * hi16(vA.z) + gB * hi16(vB.z);
    acc[6] += gA * lo16(vA.w) + gB * lo16(vB.w);
    acc[7] += gA * hi16(vA.w) + gB * hi16(vB.w);
  }
  for (; i + 1 < end; i += 2) {
    uint2 rA = csr[i + half];
    uint4 vA = r1[(size_t)rA.x * 32 + sl];
    float gA = __uint_as_float(rA.y) * inv;
    acc[0] += gA * lo16(vA.x); acc[1] += gA * hi16(vA.x);
    acc[2] += gA * lo16(vA.y); acc[3] += gA * hi16(vA.y);
    acc[4] += gA * lo16(vA.z); acc[5] += gA * hi16(vA.z);
    acc[6] += gA * lo16(vA.w); acc[7] += gA * hi16(vA.w);
  }
  if (i < end && half == 0) {
    uint2 rA = csr[i];
    uint4 vA = r1[(size_t)rA.x * 32 + sl];
    float gA = __uint_as_float(rA.y) * inv;
    acc[0] += gA * lo16(vA.x); acc[1] += gA * hi16(vA.x);
    acc[2] += gA * lo16(vA.y); acc[3] += gA * hi16(vA.y);
    acc[4] += gA * lo16(vA.z); acc[5] += gA * hi16(vA.z);
    acc[6] += gA * lo16(vA.w); acc[7] += gA * hi16(vA.w);
  }
  #pragma unroll
  for (int j = 0; j < 8; ++j) acc[j] += __shfl_xor(acc[j], 32, 64);
  if (half == 0) {
    uint4 va = ar[(size_t)nd * 32 + sl];
    uint4 vb = r1[(size_t)nd * 32 + sl];
    acc[0] += lo16(va.x) + lo16(vb.x); acc[1] += hi16(va.x) + hi16(vb.x);
    acc[2] += lo16(va.y) + lo16(vb.y); acc[3] += hi16(va.y) + hi16(vb.y);
    acc[4] += lo16(va.z) + lo16(vb.z); acc[5] += hi16(va.z) + hi16(vb.z);
    acc[6] += lo16(va.w) + lo16(vb.w); acc[7] += hi16(va.w) + hi16(vb.w);
    float4* xo = (float4*)&xt[(size_t)d * SS + sl * 8];
    float4 w0; w0.x = acc[0]; w0.y = acc[1]; w0.z = acc[2]; w0.w = acc[3];
    float4 w1; w1.x = acc[4]; w1.y = acc[5]; w1.z = acc[6]; w1.w = acc[7];
    xo[0] = w0; xo[1] = w1;
  }
}

// ---------- 8. GEMM1: partial[z][p][s] = Wt-slice^T x xt-slice ----------
__global__ __launch_bounds__(256) void k_gemm1(
    const float* __restrict__ xt, const float* __restrict__ Wt,
    float* __restrict__ partial) {
  __shared__ float As[SUB][64];   // [k][s]
  __shared__ float Ws[SUB][68];   // [k][p] padded
  int tid = threadIdx.x;
  int s0 = blockIdx.x * 64, p0 = blockIdx.y * 64, d0 = blockIdx.z * KCH;
  int ts = tid & 15, tp = tid >> 4;
  float acc[4][4];
  #pragma unroll
  for (int i = 0; i < 4; ++i)
    #pragma unroll
    for (int j = 0; j < 4; ++j) acc[i][j] = 0.f;

  for (int kt = 0; kt < KCH / SUB; ++kt) {
    int dd = d0 + kt * SUB;
    #pragma unroll
    for (int i = tid; i < SUB * 64; i += 256) {
      int r = i >> 6, c = i & 63;
      As[r][c] = xt[(size_t)(dd + r) * SS + s0 + c];
    }
    #pragma unroll
    for (int i = tid; i < SUB * 64; i += 256) {
      int r = i >> 6, c = i & 63;
      Ws[r][c] = Wt[(size_t)(dd + r) * 512 + p0 + c];
    }
    __syncthreads();
    #pragma unroll
    for (int kk = 0; kk < SUB; ++kk) {
      float4 a = *(const float4*)&As[kk][ts * 4];
      float4 b = *(const float4*)&Ws[kk][tp * 4];
      acc[0][0] += a.x * b.x; acc[0][1] += a.x * b.y; acc[0][2] += a.x * b.z; acc[0][3] += a.x * b.w;
      acc[1][0] += a.y * b.x; acc[1][1] += a.y * b.y; acc[1][2] += a.y * b.z; acc[1][3] += a.y * b.w;
      acc[2][0] += a.z * b.x; acc[2][1] += a.z * b.y; acc[2][2] += a.z * b.z; acc[2][3] += a.z * b.w;
      acc[3][0] += a.w * b.x; acc[3][1] += a.w * b.y; acc[3][2] += a.w * b.z; acc[3][3] += a.w * b.w;
    }
    __syncthreads();
  }
  float* dstp = partial + (size_t)blockIdx.z * 512 * 256;
  #pragma unroll
  for (int j = 0; j < 4; ++j) {
    int p = p0 + tp * 4 + j;
    float4 w; w.x = acc[0][j]; w.y = acc[1][j]; w.z = acc[2][j]; w.w = acc[3][j];
    *(float4*)&dstp[(size_t)p * 256 + s0 + ts * 4] = w;
  }
}

// ---------- 9. reduce partials + bias + relu ----------
__global__ __launch_bounds__(256) void k_reduce(
    const float* __restrict__ partial, const float* __restrict__ bmp,
    float* __restrict__ h1t) {
  int idx = blockIdx.x * 256 + threadIdx.x;
  if (idx >= PP * SS) return;
  float acc = bmp[idx >> 8];
  #pragma unroll
  for (int z = 0; z < ZSPLIT; ++z) acc += partial[(size_t)z * 512 * 256 + idx];
  h1t[idx] = fmaxf(acc, 0.0f);
}

// ---------- 10. h2t[ph][s]: one wave per (ph, 64-s block), 10-way ILP ----------
__global__ __launch_bounds__(64) void k_h2(
    const float* __restrict__ h1t, const float* __restrict__ Wph,
    const float* __restrict__ bph, float* __restrict__ h2t) {
  int ph = blockIdx.x;
  int s = blockIdx.y * 64 + threadIdx.x;
  const float* w = &Wph[(size_t)ph * PP];
  float acc[10];
  #pragma unroll
  for (int j = 0; j < 10; ++j) acc[j] = 0.f;
  for (int k = 0; k < 50; ++k) {
    int p = k * 10;
    #pragma unroll
    for (int j = 0; j < 10; ++j)
      acc[j] = fmaf(h1t[(size_t)(p + j) * SS + s], w[p + j], acc[j]);
  }
  float t = ((acc[0] + acc[1]) + (acc[2] + acc[3])) + ((acc[4] + acc[5]) + (acc[6] + acc[7])) + (acc[8] + acc[9]);
  h2t[(size_t)ph * SS + s] = fmaxf(t + bph[ph], 0.0f);
}

// ---------- 11. out[s,:] = softmax ----------
__global__ __launch_bounds__(256) void k_out(
    const float* __restrict__ h2t, const float* __restrict__ Wpo,
    const float* __restrict__ bpo, float* __restrict__ out) {
  int s = threadIdx.x;
  float o0 = bpo[0], o1 = bpo[1];
  for (int ph = 0; ph < PHH; ++ph) {
    float v = h2t[(size_t)ph * SS + s];
    o0 += v * Wpo[ph];
    o1 += v * Wpo[PHH + ph];
  }
  float mx = fmaxf(o0, o1);
  float e0 = __expf(o0 - mx), e1 = __expf(o1 - mx);
  float inv = 1.0f / (e0 + e1);
  out[2 * s] = e0 * inv;
  out[2 * s + 1] = e1 * inv;
}

extern "C" void kernel_launch(void* const* d_in, const int* in_sizes, int n_in,
                              void* d_out, int out_size, void* d_ws, size_t ws_size,
                              hipStream_t stream) {
  const float* lnc   = (const float*)d_in[0];
  const float* mi    = (const float*)d_in[1];
  const float* mdat  = (const float*)d_in[2];
  const int*   src   = (const int*)d_in[3];
  const int*   dst   = (const int*)d_in[4];
  const int*   dem   = (const int*)d_in[5];
  const float* attnl = (const float*)d_in[6];
  const float* attnr = (const float*)d_in[7];
  const float* bias0 = (const float*)d_in[8];
  const float* pmask = (const float*)d_in[9];
  const float* Wmp   = (const float*)d_in[10];
  const float* bmp   = (const float*)d_in[11];
  const float* Wph   = (const float*)d_in[12];
  const float* bph   = (const float*)d_in[13];
  const float* Wpo   = (const float*)d_in[14];
  const float* bpo   = (const float*)d_in[15];
  float* out = (float*)d_out;

  char* ws = (char*)d_ws;
  size_t off = 0;
  auto alloc = [&](size_t bytes) -> char* {
    char* p = ws + off;
    off += (bytes + 255) & ~(size_t)255;
    return p;
  };
  float*    mean    = (float*)alloc(SS * 4);
  float*    invstd  = (float*)alloc(SS * 4);
  float*    a1      = (float*)alloc(NN * 4);
  float*    a2      = (float*)alloc(NN * 4);
  float*    rowsum4 = (float*)alloc((size_t)4 * NN * 4);
  float*    zinv    = (float*)alloc(NN * 4);
  int*      counts  = (int*)alloc(NN * 4);
  int*      offs    = (int*)alloc((NN + 1) * 4);
  int*      cursor  = (int*)alloc(NN * 4);
  uint2*    csr     = (uint2*)alloc((size_t)EE * 8);
  ushort_t* a_rna   = (ushort_t*)alloc((size_t)NN * SS * 2);
  ushort_t* rna1    = (ushort_t*)alloc((size_t)NN * SS * 2);
  float*    xt      = (float*)alloc((size_t)DD * SS * 4);
  float*    Wt      = (float*)alloc((size_t)DD * 512 * 4);
  float*    partial = (float*)alloc((size_t)ZSPLIT * 512 * 256 * 4);
  float*    h1t     = (float*)alloc((size_t)PP * SS * 4);
  float*    h2t     = (float*)alloc((size_t)PHH * SS * 4);

  k_meanstd<<<SS, 256, 0, stream>>>(lnc, mi, mdat, mean, invstd);
  k_prep<<<3528, dim3(32, 8), 0, stream>>>(lnc, mi, mdat, mean, invstd, a_rna,
                                           rowsum4, Wmp, pmask, Wt, counts);
  k_count2<<<2579, 256, 0, stream>>>(dst, counts, rowsum4, attnl, attnr, a1, a2);
  k_scan<<<1, 1024, 0, stream>>>(counts, offs, cursor);
  k_fill<<<(EE + 255) / 256, 256, 0, stream>>>(src, dst, a1, a2, bias0, cursor, csr);
  k_agg<<<NN / 4, 256, 0, stream>>>(csr, offs, a_rna, rna1, zinv);
  k_pass2x<<<DD / 4, 256, 0, stream>>>(dem, offs, csr, a_rna, rna1, zinv, xt);
  k_gemm1<<<dim3(SS / 64, 8, ZSPLIT), 256, 0, stream>>>(xt, Wt, partial);
  k_reduce<<<(PP * SS + 255) / 256, 256, 0, stream>>>(partial, bmp, h1t);
  k_h2<<<dim3(PHH, SS / 64), 64, 0, stream>>>(h1t, Wph, bph, h2t);
  k_out<<<1, SS, 0, stream>>>(h2t, Wpo, bpo, out);
}